// Round 36
// baseline (406.914 us; speedup 1.0000x reference)
//
#include <hip/hip_runtime.h>
#include <hip/hip_bf16.h>
#include <math.h>

typedef unsigned short u16;
typedef __attribute__((ext_vector_type(8))) short bf16x8;
typedef __attribute__((ext_vector_type(4))) float f32x4;

#define Bb 16
#define Cch 512
#define Ss 1024
#define NHh 8
#define DHh 64
#define CPG 64
#define EPSV 1e-5f
#define R_TOTAL (Bb*Ss)   // 16384
#define QSCL 0.18033688011112042f   // 0.125 * log2(e)
#define DEFER_THR 8.0f    // T13: skip O-rescale while tile-max growth <= 8 (log2 domain)

__device__ inline u16 f2bf(float f) {
    unsigned int u = __float_as_uint(f);
    unsigned int r = (u + 0x7fffu + ((u >> 16) & 1u)) >> 16;
    return (u16)r;
}
__device__ inline u16 f2bf_rz(float f) { return (u16)(__float_as_uint(f) >> 16); }
__device__ inline float bf2f(u16 v) { return __uint_as_float((unsigned)v << 16); }
__device__ inline float exp2_raw(float x) {
    float r; asm("v_exp_f32 %0, %1" : "=v"(r) : "v"(x)); return r;
}
__device__ inline float rcp_raw(float x) {
    float r; asm("v_rcp_f32 %0, %1" : "=v"(r) : "v"(x)); return r;
}
// branchless exact-GELU via Abramowitz-Stegun 7.1.26 erf (max err 1.5e-7)
__device__ inline float gelu_f(float g) {
    float z = fabsf(g) * 0.70710678118654752f;
    float t = rcp_raw(1.0f + 0.3275911f * z);
    float poly = t * (0.254829592f + t * (-0.284496736f + t * (1.421413741f +
                 t * (-1.453152027f + t * 1.061405429f))));
    float e = exp2_raw(-z * z * 1.44269504089f);
    float erfa = 1.0f - poly * e;
    float erfv = (g < 0.f) ? -erfa : erfa;
    return 0.5f * g * (1.0f + erfv);
}

// swizzles: 16B chunk XOR'd by row&7 within stride-64 rows (proven clean r14-r25).
__device__ inline int swz(int row, int chunk) {      // [R][64] tile
    return row * 64 + ((chunk ^ (row & 7)) * 8);
}
// 128-wide tiles split into two stride-64 halves (chunk bit 3 = half select, wave-uniform)
__device__ inline int psw(int row, int chunk) {      // Ps[128][128]: halves of [128][64]
    return ((chunk >> 3) << 13) + row * 64 + (((chunk & 7) ^ (row & 7)) * 8);
}
__device__ inline int vsw(int row, int chunk) {      // Vt[64][128]: halves of [64][64]
    return ((chunk >> 3) << 12) + row * 64 + (((chunk & 7) ^ (row & 7)) * 8);
}
__device__ inline int swzg(int r, int c) {           // GEMM [R][32] tile
    int span = r >> 1;
    int c8 = ((r & 1) << 2) | c;
    return span * 64 + ((c8 ^ (span & 7)) * 8);
}

// ---------------- GroupNorm partial stats: 256 blocks (2 halves per (b,g)) ----------
__global__ __launch_bounds__(256) void gn_stats(const float* __restrict__ x,
                                                float* __restrict__ pstats) {
    int bgh = blockIdx.x;            // 0..255: (b*8+g)*2 + half
    int bg = bgh >> 1, half = bgh & 1;
    int b = bg >> 3, g = bg & 7;
    const float4* base = (const float4*)(x + ((size_t)b * Cch + (size_t)g * CPG) * Ss)
                         + (size_t)half * (CPG * Ss / 8);
    float s = 0.f, ss = 0.f;
    for (int i = threadIdx.x; i < CPG * Ss / 8; i += 256) {
        float4 v = base[i];
        s  += v.x + v.y + v.z + v.w;
        ss += v.x * v.x + v.y * v.y + v.z * v.z + v.w * v.w;
    }
    for (int o = 32; o > 0; o >>= 1) { s += __shfl_down(s, o); ss += __shfl_down(ss, o); }
    __shared__ float red[2][4];
    int wid = threadIdx.x >> 6, lane = threadIdx.x & 63;
    if (lane == 0) { red[0][wid] = s; red[1][wid] = ss; }
    __syncthreads();
    if (threadIdx.x == 0) {
        pstats[bgh * 2]     = red[0][0] + red[0][1] + red[0][2] + red[0][3];
        pstats[bgh * 2 + 1] = red[1][0] + red[1][1] + red[1][2] + red[1][3];
    }
}

// ---------------- GroupNorm apply + transpose -> bf16 (B,S,C); combines partials ------
__global__ __launch_bounds__(256) void gn_apply_t_bf(const float* __restrict__ x,
                                                     const float* __restrict__ pstats,
                                                     const float* __restrict__ gw,
                                                     const float* __restrict__ gb,
                                                     u16* __restrict__ ht) {
    __shared__ float tile[32][33];
    int b  = blockIdx.z;
    int c0 = blockIdx.y * 32;
    int s0 = blockIdx.x * 32;
    int tx = threadIdx.x, ty = threadIdx.y;
    const float inv_n = 1.0f / (CPG * Ss);
#pragma unroll
    for (int i = 0; i < 4; i++) {
        int c = c0 + ty + i * 8;
        int g = c >> 6;
        int bg = b * 8 + g;
        float S1 = pstats[(bg * 2) * 2]     + pstats[(bg * 2 + 1) * 2];
        float S2 = pstats[(bg * 2) * 2 + 1] + pstats[(bg * 2 + 1) * 2 + 1];
        float mu = S1 * inv_n;
        float var = S2 * inv_n - mu * mu;
        float rs = rsqrtf(var + EPSV);
        float v = x[((size_t)b * Cch + c) * Ss + s0 + tx];
        tile[ty + i * 8][tx] = (v - mu) * rs * gw[c] + gb[c];
    }
    __syncthreads();
#pragma unroll
    for (int i = 0; i < 4; i++) {
        int s = s0 + ty + i * 8;
        ht[((size_t)b * Ss + s) * Cch + c0 + tx] = f2bf(tile[tx][ty + i * 8]);
    }
}

// ---------------- fused weight prep: ALL conversions/transposes in 1 launch ----------
__global__ __launch_bounds__(256) void prep_all(const float* __restrict__ pin_w,
                                                const float* __restrict__ pout_w,
                                                u16* __restrict__ pinB,
                                                u16* __restrict__ poutB,
                                                const float* __restrict__ wq,
                                                const float* __restrict__ wk,
                                                const float* __restrict__ wv,
                                                const float* __restrict__ wo,
                                                u16* __restrict__ wqT,
                                                u16* __restrict__ wkT,
                                                u16* __restrict__ wvT,
                                                u16* __restrict__ woT,
                                                const float* __restrict__ wg,
                                                u16* __restrict__ wgT,
                                                const float* __restrict__ wd,
                                                u16* __restrict__ wdT) {
    __shared__ float tile[32][33];
    int bid = blockIdx.x;
    int tx = threadIdx.x, ty = threadIdx.y;
    int tid = ty * 32 + tx;
    if (bid < 512) {
        int base = bid * 1024 + tid * 4;
        const float* src; u16* dst; int off;
        if (base < 262144) { src = pin_w;  dst = pinB;  off = base; }
        else               { src = pout_w; dst = poutB; off = base - 262144; }
        float4 v = *(const float4*)&src[off];
        ushort4 o;
        o.x = f2bf(v.x); o.y = f2bf(v.y); o.z = f2bf(v.z); o.w = f2bf(v.w);
        *(ushort4*)&dst[off] = o;
        return;
    }
    const float* in; u16* outp; int c0, r0, C, R; float scl = 1.0f;
    if (bid < 1536) {
        int z = (bid - 512) >> 8, rem = (bid - 512) & 255;
        switch (z) {
            case 0: in = wq; outp = wqT; scl = QSCL; break;
            case 1: in = wk; outp = wkT; break;
            case 2: in = wv; outp = wvT; break;
            default: in = wo; outp = woT; break;
        }
        c0 = (rem & 15) * 32; r0 = (rem >> 4) * 32; C = 512; R = 512;
    } else if (bid < 3584) {
        int rem = bid - 1536;
        in = wg; outp = wgT; C = 4096; R = 512;
        c0 = (rem & 127) * 32; r0 = (rem >> 7) * 32;
    } else {
        int rem = bid - 3584;
        in = wd; outp = wdT; C = 512; R = 2048;
        c0 = (rem & 15) * 32; r0 = (rem >> 4) * 32;
    }
#pragma unroll
    for (int i = 0; i < 4; i++)
        tile[ty + i * 8][tx] = in[(size_t)(r0 + ty + i * 8) * C + c0 + tx] * scl;
    __syncthreads();
#pragma unroll
    for (int i = 0; i < 4; i++)
        outp[(size_t)(c0 + ty + i * 8) * R + r0 + tx] = f2bf(tile[tx][ty + i * 8]);
}

// ---------------- per-head V transpose: vb [b][s][512] -> vt [(b*8+h)][64][1024] ----------
__global__ __launch_bounds__(256) void vtrans(const u16* __restrict__ in,
                                              u16* __restrict__ outp) {
    __shared__ u16 tile[64][66];
    int s0 = blockIdx.x * 64, h = blockIdx.y, b = blockIdx.z;
    const u16* src = in + ((size_t)b * Ss + s0) * Cch + h * 64;
    int r = threadIdx.x >> 3, c8 = (threadIdx.x & 7) * 8;
#pragma unroll
    for (int p = 0; p < 2; p++) {
        int rr = r + p * 32;
        *(int4*)&tile[rr][c8] = *(const int4*)&src[(size_t)rr * Cch + c8];
    }
    __syncthreads();
    u16* dst = outp + ((size_t)(b * 8 + h) * 64) * Ss + s0;
#pragma unroll
    for (int p = 0; p < 2; p++) {
        int d = r + p * 32;
        u16 vals[8];
#pragma unroll
        for (int e = 0; e < 8; e++) vals[e] = tile[c8 + e][d];
        *(int4*)&dst[(size_t)d * Ss + c8] = *(int4*)vals;
    }
}

// ---------------- LayerNorm rows (bf16 in, bf16 out) ----------------
__global__ __launch_bounds__(256) void layer_norm_rows_bf(const u16* __restrict__ in,
                                                          const float* __restrict__ w,
                                                          const float* __restrict__ bb,
                                                          u16* __restrict__ outp) {
    int row = blockIdx.x;
    const u16* p = in + (size_t)row * Cch;
    int i0 = threadIdx.x * 2;
    ushort2 u = *(const ushort2*)&p[i0];
    float v0 = bf2f(u.x), v1 = bf2f(u.y);
    float s = v0 + v1, ss = v0 * v0 + v1 * v1;
    for (int o = 32; o > 0; o >>= 1) { s += __shfl_down(s, o); ss += __shfl_down(ss, o); }
    __shared__ float red[2][4];
    __shared__ float mu_s, rs_s;
    int wid = threadIdx.x >> 6, lane = threadIdx.x & 63;
    if (lane == 0) { red[0][wid] = s; red[1][wid] = ss; }
    __syncthreads();
    if (threadIdx.x == 0) {
        float S1 = red[0][0] + red[0][1] + red[0][2] + red[0][3];
        float S2 = red[1][0] + red[1][1] + red[1][2] + red[1][3];
        float mu = S1 * (1.0f / Cch);
        float var = S2 * (1.0f / Cch) - mu * mu;
        mu_s = mu; rs_s = rsqrtf(var + EPSV);
    }
    __syncthreads();
    float mu = mu_s, rs = rs_s;
    outp[(size_t)row * Cch + i0]     = f2bf((v0 - mu) * rs * w[i0] + bb[i0]);
    outp[(size_t)row * Cch + i0 + 1] = f2bf((v1 - mu) * rs * w[i0 + 1] + bb[i0 + 1]);
}

// ---------------- MFMA GEMM: out(MxN) = A(MxK bf16) @ Bt(NxK bf16)^T ----------------
// r36: 128x128 tile, BK=32, 256 thr = 4 waves (2x2), per-wave 64x64 (same per-wave work
// as r33's 256x128/8-wave) -> grid doubles to >=2 blocks/CU, adding the cross-block TLP
// the 1-block/CU config lacked (r30/r31 lesson: block overlap is the latency hider).
// dbuf 1-barrier retained. Dead ends: r28 BK=64 (spill), r32 depth-2, r34 gload_lds.
// EPI: 0 = bf16; 1 = fp32 +bias; 6 = bf16 +bias; 7 = bf16 +bias + bf16 residual in-place;
//      8 = bf16 routed qkv (outb base = qb; col>>9 selects q/k/v slot, 8388608 apart).
template<int EPI>
__global__ __launch_bounds__(256) void mfma_gemm(const u16* __restrict__ A,
                                                 const u16* __restrict__ Bt,
                                                 const float* __restrict__ bias,
                                                 float* __restrict__ fout,
                                                 u16* __restrict__ outb,
                                                 int K, int N) {
    __shared__ u16 As[2][128 * 32];
    __shared__ u16 Bs[2][128 * 32];
    int tid = threadIdx.x;
    int m0 = blockIdx.y * 128, n0 = blockIdx.x * 128;
    int wave = tid >> 6, lane = tid & 63;
    int wr = wave >> 1, wc = wave & 1;      // 2x2 wave grid
    int l15 = lane & 15, l4 = lane >> 4;

    f32x4 zero4 = {0.f, 0.f, 0.f, 0.f};
    f32x4 acc[4][4];
#pragma unroll
    for (int i = 0; i < 4; i++)
#pragma unroll
        for (int j = 0; j < 4; j++) acc[i][j] = zero4;

    // staging: 128 rows x 4 chunks each for A and B; thread -> row tid>>1, pair {c0,c0+1}
    int srow = tid >> 1;
    int sc0  = (tid & 1) * 2;
    int se   = sc0 * 8;

    const u16* pa = A  + (size_t)(m0 + srow) * K + se;
    const u16* pb = Bt + (size_t)(n0 + srow) * K + se;

    // prologue: tile 0 -> buf 0; issue tile 1 loads (K >= 64 always here)
    int4 ra0 = *(const int4*)pa;
    int4 ra1 = *(const int4*)(pa + 8);
    int4 rb0 = *(const int4*)pb;
    int4 rb1 = *(const int4*)(pb + 8);
    *(int4*)&As[0][swzg(srow, sc0)]     = ra0;
    *(int4*)&As[0][swzg(srow, sc0 + 1)] = ra1;
    *(int4*)&Bs[0][swzg(srow, sc0)]     = rb0;
    *(int4*)&Bs[0][swzg(srow, sc0 + 1)] = rb1;
    ra0 = *(const int4*)(pa + 32);
    ra1 = *(const int4*)(pa + 40);
    rb0 = *(const int4*)(pb + 32);
    rb1 = *(const int4*)(pb + 40);
    __syncthreads();

    int p = 0;
    for (int kt = 0; kt < K; kt += 32) {
        bf16x8 af[4], bfr[4];
#pragma unroll
        for (int mi = 0; mi < 4; mi++)
            af[mi] = *(const bf16x8*)&As[p][swzg(wr * 64 + mi * 16 + l15, l4)];
#pragma unroll
        for (int nj = 0; nj < 4; nj++)
            bfr[nj] = *(const bf16x8*)&Bs[p][swzg(wc * 64 + nj * 16 + l15, l4)];
#pragma unroll
        for (int mi = 0; mi < 4; mi++)
#pragma unroll
            for (int nj = 0; nj < 4; nj++)
                acc[mi][nj] = __builtin_amdgcn_mfma_f32_16x16x32_bf16(af[mi], bfr[nj], acc[mi][nj], 0, 0, 0);
        if (kt + 32 < K) {
            *(int4*)&As[p ^ 1][swzg(srow, sc0)]     = ra0;
            *(int4*)&As[p ^ 1][swzg(srow, sc0 + 1)] = ra1;
            *(int4*)&Bs[p ^ 1][swzg(srow, sc0)]     = rb0;
            *(int4*)&Bs[p ^ 1][swzg(srow, sc0 + 1)] = rb1;
            if (kt + 64 < K) {
                ra0 = *(const int4*)(pa + kt + 64);
                ra1 = *(const int4*)(pa + kt + 72);
                rb0 = *(const int4*)(pb + kt + 64);
                rb1 = *(const int4*)(pb + kt + 72);
            }
        }
        __syncthreads();
        p ^= 1;
    }

#pragma unroll
    for (int mi = 0; mi < 4; mi++)
#pragma unroll
        for (int nj = 0; nj < 4; nj++)
#pragma unroll
            for (int r = 0; r < 4; r++) {
                int row = m0 + wr * 64 + mi * 16 + l4 * 4 + r;
                int col = n0 + wc * 64 + nj * 16 + l15;
                float v = acc[mi][nj][r];
                if constexpr (EPI == 0) {
                    outb[(size_t)row * N + col] = f2bf(v);
                } else if constexpr (EPI == 1) {
                    fout[(size_t)row * N + col] = v + bias[col];
                } else if constexpr (EPI == 6) {
                    outb[(size_t)row * N + col] = f2bf(v + bias[col]);
                } else if constexpr (EPI == 7) {
                    size_t idx = (size_t)row * N + col;
                    v += bias[col] + bf2f(outb[idx]);
                    outb[idx] = f2bf(v);
                } else if constexpr (EPI == 8) {
                    size_t idx = (size_t)(col >> 9) * 8388608 + (size_t)row * 512 + (col & 511);
                    outb[idx] = f2bf(v);
                }
            }
}

// ---------------- GEGLU MFMA: 256x64(x2 halves) tile, 8 waves, fused exact GELU --------
// Single-buffer 2-barrier (r31 cherry-pick): geglu runs 2048 blocks and relies on
// multi-block/CU overlap; dbuf's 48KB LDS cut occupancy 36->22 and cost 7us (r30).
__global__ __launch_bounds__(512) void geglu_mfma(const u16* __restrict__ A,
                                                  const u16* __restrict__ WgT,  // [4096][512]
                                                  const float* __restrict__ bg,
                                                  u16* __restrict__ ag) {
    __shared__ u16 As[256 * 32];
    __shared__ u16 Bs1[64 * 32];
    __shared__ u16 Bs2[64 * 32];
    const int K = 512;
    int tid = threadIdx.x;
    int m0 = blockIdx.y * 256, n0 = blockIdx.x * 64;
    int wave = tid >> 6, lane = tid & 63;
    int wr = wave >> 1, wc = wave & 1;
    int l15 = lane & 15, l4 = lane >> 4;

    f32x4 zero4 = {0.f, 0.f, 0.f, 0.f};
    f32x4 accA[4][2], accG[4][2];
#pragma unroll
    for (int i = 0; i < 4; i++) { accA[i][0] = zero4; accA[i][1] = zero4; accG[i][0] = zero4; accG[i][1] = zero4; }

    int srow = tid >> 1;
    int sc0  = (tid & 1) * 2;
    int se   = sc0 * 8;
    int bsel = tid >> 8;
    int bt   = tid & 255;
    int brow = bt >> 2;
    int bch  = bt & 3;
    int bqe  = bch * 8;
    const u16* gbp = WgT + (size_t)(bsel * 2048 + n0 + brow) * K + bqe;

    int4 ra0, ra1, rb;
    {
        const u16* pa = A + (size_t)(m0 + srow) * K + se;
        ra0 = *(const int4*)pa; ra1 = *(const int4*)(pa + 8);
        rb = *(const int4*)gbp;
    }
    for (int kt = 0; kt < K; kt += 32) {
        __syncthreads();
        *(int4*)&As[swzg(srow, sc0)]     = ra0;
        *(int4*)&As[swzg(srow, sc0 + 1)] = ra1;
        if (bsel == 0) *(int4*)&Bs1[swzg(brow, bch)] = rb;
        else           *(int4*)&Bs2[swzg(brow, bch)] = rb;
        __syncthreads();
        int kn = kt + 32;
        if (kn < K) {
            const u16* pa = A + (size_t)(m0 + srow) * K + kn + se;
            ra0 = *(const int4*)pa; ra1 = *(const int4*)(pa + 8);
            rb = *(const int4*)(gbp + kn);
        }
        bf16x8 af[4], b1[2], b2[2];
#pragma unroll
        for (int mi = 0; mi < 4; mi++)
            af[mi] = *(const bf16x8*)&As[swzg(wr * 64 + mi * 16 + l15, l4)];
#pragma unroll
        for (int nj = 0; nj < 2; nj++) {
            b1[nj] = *(const bf16x8*)&Bs1[swzg(wc * 32 + nj * 16 + l15, l4)];
            b2[nj] = *(const bf16x8*)&Bs2[swzg(wc * 32 + nj * 16 + l15, l4)];
        }
#pragma unroll
        for (int mi = 0; mi < 4; mi++)
#pragma unroll
            for (int nj = 0; nj < 2; nj++) {
                accA[mi][nj] = __builtin_amdgcn_mfma_f32_16x16x32_bf16(af[mi], b1[nj], accA[mi][nj], 0, 0, 0);
                accG[mi][nj] = __builtin_amdgcn_mfma_f32_16x16x32_bf16(af[mi], b2[nj], accG[mi][nj], 0, 0, 0);
            }
    }

#pragma unroll
    for (int mi = 0; mi < 4; mi++)
#pragma unroll
        for (int nj = 0; nj < 2; nj++)
#pragma unroll
            for (int r = 0; r < 4; r++) {
                int row = m0 + wr * 64 + mi * 16 + l4 * 4 + r;
                int col = n0 + wc * 32 + nj * 16 + l15;
                float a = accA[mi][nj][r] + bg[col];
                float g = accG[mi][nj][r] + bg[2048 + col];
                ag[(size_t)row * 2048 + col] = f2bf(a * gelu_f(g));
            }
}

// ---------------- MFMA flash attention: QBLK=128, KVBLK=128, reg-prefetched staging ----
// Grid roles: x = h (fastest), y = q-block -> K/V-sharing blocks on same XCD (L2 reuse).
// T13 defer-max (r35, kept): skip O-rescale while growth <= THR.
__global__ __launch_bounds__(512) void flash_attn_mfma(const u16* __restrict__ q,
                                                       const u16* __restrict__ k,
                                                       const u16* __restrict__ vt,  // [b*8+h][64][1024]
                                                       u16* __restrict__ o) {
    __shared__ u16 Ps[2 * 128 * 64];
    __shared__ u16 Ks[128 * 64];
    __shared__ u16 Vt[2 * 64 * 64];
    const int tid = threadIdx.x;
    const int h = blockIdx.x, b = blockIdx.z;
    const int q0 = blockIdx.y * 128;
    const size_t hb  = (size_t)b * Ss * Cch + (size_t)h * DHh;
    const size_t vhb = ((size_t)(b * NHh + h) * DHh) * Ss;

    const int wq = tid >> 6;               // 0..7: wave owns q-rows wq*16..wq*16+15
    const int lane = tid & 63;
    const int l15 = lane & 15, l4 = lane >> 4;

    // staging thread maps (fixed per thread)
    const int kr = tid >> 2, kc = (tid & 3) * 2;           // K: row, chunk pair
    const int vf = tid >> 8, vtn = tid & 255;              // V: half, thread-in-half
    const int vd = vtn >> 2, vc = (vtn & 3) * 2;           // V: row, chunk pair
    const u16* kbase = k + hb + (size_t)kr * Cch + (size_t)kc * 8;
    const u16* vbase = vt + vhb + (size_t)vd * Ss + vf * 64 + (size_t)vc * 8;

    // stage Q (128x64) into Ps half 0 (chunks 0..7)
    {
        int r = tid >> 2, ch = (tid & 3) * 2;
        const u16* src = q + hb + (size_t)(q0 + r) * Cch;
        *(int4*)&Ps[psw(r, ch)]     = *(const int4*)(src + ch * 8);
        *(int4*)&Ps[psw(r, ch + 1)] = *(const int4*)(src + (ch + 1) * 8);
    }
    __syncthreads();
    bf16x8 aq[2];
    aq[0] = *(const bf16x8*)&Ps[psw(wq * 16 + l15, 0 * 4 + l4)];
    aq[1] = *(const bf16x8*)&Ps[psw(wq * 16 + l15, 1 * 4 + l4)];

    f32x4 zero4 = {0.f, 0.f, 0.f, 0.f};
    f32x4 oacc[4];
    float m_[4], l_[4];
#pragma unroll
    for (int j = 0; j < 4; j++) oacc[j] = zero4;
#pragma unroll
    for (int r = 0; r < 4; r++) { m_[r] = -1e30f; l_[r] = 0.f; }

    // prologue: load tile 0's K/V into registers
    int4 rk0, rk1, rv0, rv1;
    rk0 = *(const int4*)(kbase);
    rk1 = *(const int4*)(kbase + 8);
    rv0 = *(const int4*)(vbase);
    rv1 = *(const int4*)(vbase + 8);

    for (int t0 = 0; t0 < Ss; t0 += 128) {
        __syncthreads();                           // prev tile's LDS reads done
        *(int4*)&Ks[swz(kr, kc)]     = rk0;
        *(int4*)&Ks[swz(kr, kc + 1)] = rk1;
        *(int4*)&Vt[vsw(vd, vf * 8 + vc)]     = rv0;
        *(int4*)&Vt[vsw(vd, vf * 8 + vc + 1)] = rv1;
        __syncthreads();                           // tile ready
        if (t0 + 128 < Ss) {
            rk0 = *(const int4*)(kbase + (size_t)(t0 + 128) * Cch);
            rk1 = *(const int4*)(kbase + (size_t)(t0 + 128) * Cch + 8);
            rv0 = *(const int4*)(vbase + t0 + 128);
            rv1 = *(const int4*)(vbase + t0 + 128 + 8);
        }

        // QK^T (log2-scaled): wave's 16 q-rows x 128 t-cols
        f32x4 sacc[8];
#pragma unroll
        for (int j = 0; j < 8; j++) sacc[j] = zero4;
#pragma unroll
        for (int ks = 0; ks < 2; ks++) {
#pragma unroll
            for (int j = 0; j < 8; j++) {
                bf16x8 bk = *(const bf16x8*)&Ks[swz(j * 16 + l15, ks * 4 + l4)];
                sacc[j] = __builtin_amdgcn_mfma_f32_16x16x32_bf16(aq[ks], bk, sacc[j], 0, 0, 0);
            }
        }

        float tmv[4];
        int grew = 0;
#pragma unroll
        for (int r = 0; r < 4; r++) {
            float tm = fmaxf(fmaxf(fmaxf(sacc[0][r], sacc[1][r]), fmaxf(sacc[2][r], sacc[3][r])),
                             fmaxf(fmaxf(sacc[4][r], sacc[5][r]), fmaxf(sacc[6][r], sacc[7][r])));
            tm = fmaxf(tm, __shfl_xor(tm, 1));
            tm = fmaxf(tm, __shfl_xor(tm, 2));
            tm = fmaxf(tm, __shfl_xor(tm, 4));
            tm = fmaxf(tm, __shfl_xor(tm, 8));
            tmv[r] = tm;
            grew |= (tm > m_[r] + DEFER_THR);      // T13: tolerate growth <= THR
        }

        if (__any(grew)) {
#pragma unroll
            for (int r = 0; r < 4; r++) {
                float nm = fmaxf(m_[r], tmv[r]);
                float sc = exp2_raw(m_[r] - nm);
                m_[r] = nm;
                int row = wq * 16 + l4 * 4 + r;
                int rx = row & 7, b64 = row * 64, wi = l15 & 7, hi = l15 >> 3;
                float rs = 0.f;
#pragma unroll
                for (int j = 0; j < 8; j++) {
                    float p = exp2_raw(sacc[j][r] - nm);
                    int cnk = 2 * j + hi;
                    Ps[((cnk >> 3) << 13) + b64 + (((cnk & 7) ^ rx) * 8) + wi] = f2bf_rz(p);
                    rs += p;
                }
                l_[r] = l_[r] * sc + rs;
#pragma unroll
                for (int j = 0; j < 4; j++) oacc[j][r] *= sc;
            }
        } else {
#pragma unroll
            for (int r = 0; r < 4; r++) {
                float nm = m_[r];
                int row = wq * 16 + l4 * 4 + r;
                int rx = row & 7, b64 = row * 64, wi = l15 & 7, hi = l15 >> 3;
                float rs = 0.f;
#pragma unroll
                for (int j = 0; j < 8; j++) {
                    float p = exp2_raw(sacc[j][r] - nm);
                    int cnk = 2 * j + hi;
                    Ps[((cnk >> 3) << 13) + b64 + (((cnk & 7) ^ rx) * 8) + wi] = f2bf_rz(p);
                    rs += p;
                }
                l_[r] += rs;
            }
        }

        // PV: A=Ps (wave-private rows, k=128 -> 4 ks), Bt=Vt[d][t]
#pragma unroll
        for (int ks = 0; ks < 4; ks++) {
            bf16x8 pa = *(const bf16x8*)&Ps[psw(wq * 16 + l15, ks * 4 + l4)];
#pragma unroll
            for (int j = 0; j < 4; j++) {
                bf16x8 bv = *(const bf16x8*)&Vt[vsw(j * 16 + l15, ks * 4 + l4)];
                oacc[j] = __builtin_amdgcn_mfma_f32_16x16x32_bf16(pa, bv, oacc[j], 0, 0, 0);
            }
        }
    }

    // finalize: reduce per-lane l partials, O /= l, stage via Ps half 0, coalesced store
#pragma unroll
    for (int r = 0; r < 4; r++) {
        float lt = l_[r];
        lt += __shfl_xor(lt, 1);
        lt += __shfl_xor(lt, 2);
        lt += __shfl_xor(lt, 4);
        lt += __shfl_xor(lt, 8);
        float inv = 1.0f / lt;
        int row = wq * 16 + l4 * 4 + r;
        int rx = row & 7, b64 = row * 64, wi = l15 & 7, hi = l15 >> 3;
#pragma unroll
        for (int j = 0; j < 4; j++) {
            int cnk = 2 * j + hi;    // 0..7 (half 0)
            Ps[b64 + ((cnk ^ rx) * 8) + wi] = f2bf(oacc[j][r] * inv);
        }
    }
    __syncthreads();
    {
        int r = tid >> 2, ch = (tid & 3) * 2;
        u16* dst = o + hb + (size_t)(q0 + r) * Cch;
        *(int4*)(dst + ch * 8)       = *(const int4*)&Ps[psw(r, ch)];
        *(int4*)(dst + (ch + 1) * 8) = *(const int4*)&Ps[psw(r, ch + 1)];
    }
}

// ---------------- final: out(B,C,S) = tmp(B,S,C bf16)^T + x ----------------
__global__ __launch_bounds__(256) void final_out_bf(const u16* __restrict__ tmp,
                                                    const float* __restrict__ x,
                                                    float* __restrict__ outp) {
    __shared__ float tile[32][33];
    int b = blockIdx.z, c0 = blockIdx.y * 32, s0 = blockIdx.x * 32;
    int tx = threadIdx.x, ty = threadIdx.y;
#pragma unroll
    for (int i = 0; i < 4; i++) {
        int s = s0 + ty + i * 8;
        tile[ty + i * 8][tx] = bf2f(tmp[((size_t)b * Ss + s) * Cch + c0 + tx]);
    }
    __syncthreads();
#pragma unroll
    for (int i = 0; i < 4; i++) {
        int c = c0 + ty + i * 8;
        size_t idx = ((size_t)b * Cch + c) * Ss + s0 + tx;
        outp[idx] = tile[tx][ty + i * 8] + x[idx];
    }
}

extern "C" void kernel_launch(void* const* d_in, const int* in_sizes, int n_in,
                              void* d_out, int out_size, void* d_ws, size_t ws_size,
                              hipStream_t stream) {
    (void)in_sizes; (void)n_in; (void)out_size; (void)ws_size;
    const float* x      = (const float*)d_in[0];
    const float* gn_w   = (const float*)d_in[1];
    const float* gn_b   = (const float*)d_in[2];
    const float* pin_w  = (const float*)d_in[3];
    const float* pin_b  = (const float*)d_in[4];
    const float* ln1_w  = (const float*)d_in[5];
    const float* ln1_b  = (const float*)d_in[6];
    const float* wq     = (const float*)d_in[7];
    const float* wk     = (const float*)d_in[8];
    const float* wv     = (const float*)d_in[9];
    const float* wo     = (const float*)d_in[10];
    const float* bo     = (const float*)d_in[11];
    const float* ln3_w  = (const float*)d_in[12];
    const float* ln3_b  = (const float*)d_in[13];
    const float* wg     = (const float*)d_in[14];
    const float* bg     = (const float*)d_in[15];
    const float* wd     = (const float*)d_in[16];
    const float* bd     = (const float*)d_in[17];
    const float* pout_w = (const float*)d_in[18];
    const float* pout_b = (const float*)d_in[19];
    float* out = (float*)d_out;

    // ---- workspace layout (bytes) ----
    char* W = (char*)d_ws;
    u16* tb        = (u16*)W;                                     // t residual, bf16, 16.78 MB
    float* tmp_f32 = (float*)(W + 33554432);                      // vtb region
    u16* qb    = (u16*)(W + 67108864);                            // 16.78 MB (qb,kb,vb contiguous)
    u16* kb    = qb + 8388608;
    u16* vb    = kb + 8388608;
    u16* attnb = vb + 8388608;
    u16* Xb    = attnb + 8388608;                                 // 16.78 MB
    float* stats = (float*)(W + 67108864 + 5ull * 16777216);      // 2 KB (256 partial pairs)
    u16* wbase = (u16*)(W + 67108864 + 5ull * 16777216 + 2048);
    u16* pinB  = wbase;                 // 512*512  (already [N][K])
    u16* poutB = pinB  + 262144;
    u16* wqT   = poutB + 262144;        // [512][512] transposed, scaled by QSCL
    u16* wkT   = wqT   + 262144;        // contiguous with wqT -> [1536][512] for fused qkv
    u16* wvT   = wkT   + 262144;
    u16* woT   = wvT   + 262144;
    u16* wgT   = woT   + 262144;        // [4096][512]
    u16* wdT   = wgT   + 2097152;       // [512][2048]
    u16* ag    = qb;                    // R x 2048 bf16, aliases qb..attnb (dead by then)
    u16* vtb   = (u16*)tmp_f32;         // V^T [b*8+h][64][1024]

    dim3 tb8(32, 8);

    // partial stats (256 blocks, full machine) + fused weight prep
    gn_stats<<<256, 256, 0, stream>>>(x, stats);
    prep_all<<<4608, tb8, 0, stream>>>(pin_w, pout_w, pinB, poutB,
                                       wq, wk, wv, wo, wqT, wkT, wvT, woT,
                                       wg, wgT, wd, wdT);

    // h = GN(x) transposed -> Xb (bf16); combines stat partials
    gn_apply_t_bf<<<dim3(32, 16, 16), tb8, 0, stream>>>(x, stats, gn_w, gn_b, Xb);

    // t = h @ pin_w^T + pin_b -> tb (bf16)
    mfma_gemm<6><<<dim3(4, 128), 256, 0, stream>>>(Xb, pinB, pin_b, nullptr, tb, 512, 512);
    // tn = ln1(t) -> Xb
    layer_norm_rows_bf<<<16384, 256, 0, stream>>>(tb, ln1_w, ln1_b, Xb);
    // fused q(scaled)/k/v: N=1536, routed to qb/kb/vb
    mfma_gemm<8><<<dim3(12, 128), 256, 0, stream>>>(Xb, wqT, nullptr, nullptr, qb, 512, 1536);
    // per-head V transpose -> vtb
    vtrans<<<dim3(16, 8, 16), 256, 0, stream>>>(vb, vtb);
    // attention (MFMA, QBLK=128, KVBLK=128, prefetched, defer-max) -> attnb
    flash_attn_mfma<<<dim3(8, 8, 16), 512, 0, stream>>>(qb, kb, vtb, attnb);
    // t += attn @ wo + bo (bf16 in-place on tb)
    mfma_gemm<7><<<dim3(4, 128), 256, 0, stream>>>(attnb, woT, bo, nullptr, tb, 512, 512);
    // tn3 = ln3(t) -> Xb
    layer_norm_rows_bf<<<16384, 256, 0, stream>>>(tb, ln3_w, ln3_b, Xb);
    // ag = a * gelu(g) (bf16), aliases q/k/v/attn space
    geglu_mfma<<<dim3(32, 64), 512, 0, stream>>>(Xb, wgT, bg, ag);
    // t += ag @ wd + bd (bf16 in-place on tb)
    mfma_gemm<7><<<dim3(4, 128), 256, 0, stream>>>(ag, wdT, bd, nullptr, tb, 2048, 512);
    // tmp = t @ pout_w^T + pout_b -> Xb (bf16)
    mfma_gemm<6><<<dim3(4, 128), 256, 0, stream>>>(tb, poutB, pout_b, nullptr, Xb, 512, 512);
    // out = tmp^T + x
    final_out_bf<<<dim3(32, 16, 16), tb8, 0, stream>>>(Xb, x, out);
}

// Round 37
// 382.958 us; speedup vs baseline: 1.0626x; 1.0626x over previous
//
#include <hip/hip_runtime.h>
#include <hip/hip_bf16.h>
#include <math.h>

typedef unsigned short u16;
typedef __attribute__((ext_vector_type(8))) short bf16x8;
typedef __attribute__((ext_vector_type(4))) float f32x4;

#define Bb 16
#define Cch 512
#define Ss 1024
#define NHh 8
#define DHh 64
#define CPG 64
#define EPSV 1e-5f
#define R_TOTAL (Bb*Ss)   // 16384
#define QSCL 0.18033688011112042f   // 0.125 * log2(e)
#define DEFER_THR 8.0f    // T13: skip O-rescale while tile-max growth <= 8 (log2 domain)

__device__ inline u16 f2bf(float f) {
    unsigned int u = __float_as_uint(f);
    unsigned int r = (u + 0x7fffu + ((u >> 16) & 1u)) >> 16;
    return (u16)r;
}
__device__ inline u16 f2bf_rz(float f) { return (u16)(__float_as_uint(f) >> 16); }
__device__ inline float bf2f(u16 v) { return __uint_as_float((unsigned)v << 16); }
__device__ inline float exp2_raw(float x) {
    float r; asm("v_exp_f32 %0, %1" : "=v"(r) : "v"(x)); return r;
}
__device__ inline float rcp_raw(float x) {
    float r; asm("v_rcp_f32 %0, %1" : "=v"(r) : "v"(x)); return r;
}
// branchless exact-GELU via Abramowitz-Stegun 7.1.26 erf (max err 1.5e-7)
__device__ inline float gelu_f(float g) {
    float z = fabsf(g) * 0.70710678118654752f;
    float t = rcp_raw(1.0f + 0.3275911f * z);
    float poly = t * (0.254829592f + t * (-0.284496736f + t * (1.421413741f +
                 t * (-1.453152027f + t * 1.061405429f))));
    float e = exp2_raw(-z * z * 1.44269504089f);
    float erfa = 1.0f - poly * e;
    float erfv = (g < 0.f) ? -erfa : erfa;
    return 0.5f * g * (1.0f + erfv);
}

// swizzles: 16B chunk XOR'd by row&7 within stride-64 rows (proven clean r14-r25).
__device__ inline int swz(int row, int chunk) {      // [R][64] tile
    return row * 64 + ((chunk ^ (row & 7)) * 8);
}
// 128-wide tiles split into two stride-64 halves (chunk bit 3 = half select, wave-uniform)
__device__ inline int psw(int row, int chunk) {      // Ps[128][128]: halves of [128][64]
    return ((chunk >> 3) << 13) + row * 64 + (((chunk & 7) ^ (row & 7)) * 8);
}
__device__ inline int vsw(int row, int chunk) {      // Vt[64][128]: halves of [64][64]
    return ((chunk >> 3) << 12) + row * 64 + (((chunk & 7) ^ (row & 7)) * 8);
}
__device__ inline int swzg(int r, int c) {           // GEMM [R][32] tile
    int span = r >> 1;
    int c8 = ((r & 1) << 2) | c;
    return span * 64 + ((c8 ^ (span & 7)) * 8);
}

// ---------------- GroupNorm partial stats: 256 blocks (2 halves per (b,g)) ----------
__global__ __launch_bounds__(256) void gn_stats(const float* __restrict__ x,
                                                float* __restrict__ pstats) {
    int bgh = blockIdx.x;            // 0..255: (b*8+g)*2 + half
    int bg = bgh >> 1, half = bgh & 1;
    int b = bg >> 3, g = bg & 7;
    const float4* base = (const float4*)(x + ((size_t)b * Cch + (size_t)g * CPG) * Ss)
                         + (size_t)half * (CPG * Ss / 8);
    float s = 0.f, ss = 0.f;
    for (int i = threadIdx.x; i < CPG * Ss / 8; i += 256) {
        float4 v = base[i];
        s  += v.x + v.y + v.z + v.w;
        ss += v.x * v.x + v.y * v.y + v.z * v.z + v.w * v.w;
    }
    for (int o = 32; o > 0; o >>= 1) { s += __shfl_down(s, o); ss += __shfl_down(ss, o); }
    __shared__ float red[2][4];
    int wid = threadIdx.x >> 6, lane = threadIdx.x & 63;
    if (lane == 0) { red[0][wid] = s; red[1][wid] = ss; }
    __syncthreads();
    if (threadIdx.x == 0) {
        pstats[bgh * 2]     = red[0][0] + red[0][1] + red[0][2] + red[0][3];
        pstats[bgh * 2 + 1] = red[1][0] + red[1][1] + red[1][2] + red[1][3];
    }
}

// ---------------- GroupNorm apply + transpose -> bf16 (B,S,C); combines partials ------
__global__ __launch_bounds__(256) void gn_apply_t_bf(const float* __restrict__ x,
                                                     const float* __restrict__ pstats,
                                                     const float* __restrict__ gw,
                                                     const float* __restrict__ gb,
                                                     u16* __restrict__ ht) {
    __shared__ float tile[32][33];
    int b  = blockIdx.z;
    int c0 = blockIdx.y * 32;
    int s0 = blockIdx.x * 32;
    int tx = threadIdx.x, ty = threadIdx.y;
    const float inv_n = 1.0f / (CPG * Ss);
#pragma unroll
    for (int i = 0; i < 4; i++) {
        int c = c0 + ty + i * 8;
        int g = c >> 6;
        int bg = b * 8 + g;
        float S1 = pstats[(bg * 2) * 2]     + pstats[(bg * 2 + 1) * 2];
        float S2 = pstats[(bg * 2) * 2 + 1] + pstats[(bg * 2 + 1) * 2 + 1];
        float mu = S1 * inv_n;
        float var = S2 * inv_n - mu * mu;
        float rs = rsqrtf(var + EPSV);
        float v = x[((size_t)b * Cch + c) * Ss + s0 + tx];
        tile[ty + i * 8][tx] = (v - mu) * rs * gw[c] + gb[c];
    }
    __syncthreads();
#pragma unroll
    for (int i = 0; i < 4; i++) {
        int s = s0 + ty + i * 8;
        ht[((size_t)b * Ss + s) * Cch + c0 + tx] = f2bf(tile[tx][ty + i * 8]);
    }
}

// ---------------- fused weight prep: ALL conversions/transposes in 1 launch ----------
__global__ __launch_bounds__(256) void prep_all(const float* __restrict__ pin_w,
                                                const float* __restrict__ pout_w,
                                                u16* __restrict__ pinB,
                                                u16* __restrict__ poutB,
                                                const float* __restrict__ wq,
                                                const float* __restrict__ wk,
                                                const float* __restrict__ wv,
                                                const float* __restrict__ wo,
                                                u16* __restrict__ wqT,
                                                u16* __restrict__ wkT,
                                                u16* __restrict__ wvT,
                                                u16* __restrict__ woT,
                                                const float* __restrict__ wg,
                                                u16* __restrict__ wgT,
                                                const float* __restrict__ wd,
                                                u16* __restrict__ wdT) {
    __shared__ float tile[32][33];
    int bid = blockIdx.x;
    int tx = threadIdx.x, ty = threadIdx.y;
    int tid = ty * 32 + tx;
    if (bid < 512) {
        int base = bid * 1024 + tid * 4;
        const float* src; u16* dst; int off;
        if (base < 262144) { src = pin_w;  dst = pinB;  off = base; }
        else               { src = pout_w; dst = poutB; off = base - 262144; }
        float4 v = *(const float4*)&src[off];
        ushort4 o;
        o.x = f2bf(v.x); o.y = f2bf(v.y); o.z = f2bf(v.z); o.w = f2bf(v.w);
        *(ushort4*)&dst[off] = o;
        return;
    }
    const float* in; u16* outp; int c0, r0, C, R; float scl = 1.0f;
    if (bid < 1536) {
        int z = (bid - 512) >> 8, rem = (bid - 512) & 255;
        switch (z) {
            case 0: in = wq; outp = wqT; scl = QSCL; break;
            case 1: in = wk; outp = wkT; break;
            case 2: in = wv; outp = wvT; break;
            default: in = wo; outp = woT; break;
        }
        c0 = (rem & 15) * 32; r0 = (rem >> 4) * 32; C = 512; R = 512;
    } else if (bid < 3584) {
        int rem = bid - 1536;
        in = wg; outp = wgT; C = 4096; R = 512;
        c0 = (rem & 127) * 32; r0 = (rem >> 7) * 32;
    } else {
        int rem = bid - 3584;
        in = wd; outp = wdT; C = 512; R = 2048;
        c0 = (rem & 15) * 32; r0 = (rem >> 4) * 32;
    }
#pragma unroll
    for (int i = 0; i < 4; i++)
        tile[ty + i * 8][tx] = in[(size_t)(r0 + ty + i * 8) * C + c0 + tx] * scl;
    __syncthreads();
#pragma unroll
    for (int i = 0; i < 4; i++)
        outp[(size_t)(c0 + ty + i * 8) * R + r0 + tx] = f2bf(tile[tx][ty + i * 8]);
}

// ---------------- per-head V transpose: vb [b][s][512] -> vt [(b*8+h)][64][1024] ----------
__global__ __launch_bounds__(256) void vtrans(const u16* __restrict__ in,
                                              u16* __restrict__ outp) {
    __shared__ u16 tile[64][66];
    int s0 = blockIdx.x * 64, h = blockIdx.y, b = blockIdx.z;
    const u16* src = in + ((size_t)b * Ss + s0) * Cch + h * 64;
    int r = threadIdx.x >> 3, c8 = (threadIdx.x & 7) * 8;
#pragma unroll
    for (int p = 0; p < 2; p++) {
        int rr = r + p * 32;
        *(int4*)&tile[rr][c8] = *(const int4*)&src[(size_t)rr * Cch + c8];
    }
    __syncthreads();
    u16* dst = outp + ((size_t)(b * 8 + h) * 64) * Ss + s0;
#pragma unroll
    for (int p = 0; p < 2; p++) {
        int d = r + p * 32;
        u16 vals[8];
#pragma unroll
        for (int e = 0; e < 8; e++) vals[e] = tile[c8 + e][d];
        *(int4*)&dst[(size_t)d * Ss + c8] = *(int4*)vals;
    }
}

// ---------------- LayerNorm rows: 1 wave per row, 4 rows/block (r37) ----------------
// No LDS, no barriers: int4 load (8 bf16/lane), 6-step shfl_xor reduce, int4 store.
__global__ __launch_bounds__(256) void layer_norm_rows_bf(const u16* __restrict__ in,
                                                          const float* __restrict__ w,
                                                          const float* __restrict__ bb,
                                                          u16* __restrict__ outp) {
    int row  = blockIdx.x * 4 + (threadIdx.x >> 6);
    int lane = threadIdx.x & 63;
    int i0   = lane * 8;
    const u16* p = in + (size_t)row * Cch + i0;
    int4 v = *(const int4*)p;
    u16 us[8];
    *(int4*)us = v;
    float f[8];
    float s = 0.f, ss = 0.f;
#pragma unroll
    for (int e = 0; e < 8; e++) {
        f[e] = bf2f(us[e]);
        s += f[e];
        ss += f[e] * f[e];
    }
#pragma unroll
    for (int o = 32; o > 0; o >>= 1) {
        s  += __shfl_xor(s, o);
        ss += __shfl_xor(ss, o);
    }
    float mu = s * (1.0f / Cch);
    float var = ss * (1.0f / Cch) - mu * mu;
    float rs = rsqrtf(var + EPSV);
    float4 w0 = *(const float4*)&w[i0];
    float4 w1 = *(const float4*)&w[i0 + 4];
    float4 b0 = *(const float4*)&bb[i0];
    float4 b1 = *(const float4*)&bb[i0 + 4];
    float wv[8] = {w0.x, w0.y, w0.z, w0.w, w1.x, w1.y, w1.z, w1.w};
    float bv[8] = {b0.x, b0.y, b0.z, b0.w, b1.x, b1.y, b1.z, b1.w};
    u16 o8[8];
#pragma unroll
    for (int e = 0; e < 8; e++)
        o8[e] = f2bf((f[e] - mu) * rs * wv[e] + bv[e]);
    *(int4*)&outp[(size_t)row * Cch + i0] = *(int4*)o8;
}

// ---------------- MFMA GEMM: out(MxN) = A(MxK bf16) @ Bt(NxK bf16)^T ----------------
// 256x128 tile, BK=32, 512 thr = 8 waves (4x2). Per-wave 64x64; swizzled LDS (swzg).
// DOUBLE-BUFFERED reg staging, 1 barrier per K-step (r30/r31 proven best).
// Dead ends: r28 BK=64 (spill), r32 depth-2, r34 gload_lds, r36 128x128 tile
// (doubled B re-fetch + worse staging/MFMA ratio beat the TLP gain).
// EPI: 0 = bf16; 1 = fp32 +bias; 6 = bf16 +bias; 7 = bf16 +bias + bf16 residual in-place;
//      8 = bf16 routed qkv (outb base = qb; col>>9 selects q/k/v slot, 8388608 apart).
template<int EPI>
__global__ __launch_bounds__(512) void mfma_gemm(const u16* __restrict__ A,
                                                 const u16* __restrict__ Bt,
                                                 const float* __restrict__ bias,
                                                 float* __restrict__ fout,
                                                 u16* __restrict__ outb,
                                                 int K, int N) {
    __shared__ u16 As[2][256 * 32];
    __shared__ u16 Bs[2][128 * 32];
    int tid = threadIdx.x;
    int m0 = blockIdx.y * 256, n0 = blockIdx.x * 128;
    int wave = tid >> 6, lane = tid & 63;
    int wr = wave >> 1, wc = wave & 1;      // 4x2 wave grid
    int l15 = lane & 15, l4 = lane >> 4;

    f32x4 zero4 = {0.f, 0.f, 0.f, 0.f};
    f32x4 acc[4][4];
#pragma unroll
    for (int i = 0; i < 4; i++)
#pragma unroll
        for (int j = 0; j < 4; j++) acc[i][j] = zero4;

    int srow = tid >> 1;
    int sc0  = (tid & 1) * 2;
    int se   = sc0 * 8;
    int brow = tid >> 2;
    int bch  = tid & 3;
    int bqe  = bch * 8;

    const u16* pa = A  + (size_t)(m0 + srow) * K + se;
    const u16* pb = Bt + (size_t)(n0 + brow) * K + bqe;

    // prologue: tile 0 -> buf 0; issue tile 1 loads (K >= 64 always here)
    int4 ra0 = *(const int4*)pa;
    int4 ra1 = *(const int4*)(pa + 8);
    int4 rb0 = *(const int4*)pb;
    *(int4*)&As[0][swzg(srow, sc0)]     = ra0;
    *(int4*)&As[0][swzg(srow, sc0 + 1)] = ra1;
    *(int4*)&Bs[0][swzg(brow, bch)]     = rb0;
    ra0 = *(const int4*)(pa + 32);
    ra1 = *(const int4*)(pa + 40);
    rb0 = *(const int4*)(pb + 32);
    __syncthreads();

    int p = 0;
    for (int kt = 0; kt < K; kt += 32) {
        bf16x8 af[4], bfr[4];
#pragma unroll
        for (int mi = 0; mi < 4; mi++)
            af[mi] = *(const bf16x8*)&As[p][swzg(wr * 64 + mi * 16 + l15, l4)];
#pragma unroll
        for (int nj = 0; nj < 4; nj++)
            bfr[nj] = *(const bf16x8*)&Bs[p][swzg(wc * 64 + nj * 16 + l15, l4)];
#pragma unroll
        for (int mi = 0; mi < 4; mi++)
#pragma unroll
            for (int nj = 0; nj < 4; nj++)
                acc[mi][nj] = __builtin_amdgcn_mfma_f32_16x16x32_bf16(af[mi], bfr[nj], acc[mi][nj], 0, 0, 0);
        if (kt + 32 < K) {
            *(int4*)&As[p ^ 1][swzg(srow, sc0)]     = ra0;
            *(int4*)&As[p ^ 1][swzg(srow, sc0 + 1)] = ra1;
            *(int4*)&Bs[p ^ 1][swzg(brow, bch)]     = rb0;
            if (kt + 64 < K) {
                ra0 = *(const int4*)(pa + kt + 64);
                ra1 = *(const int4*)(pa + kt + 72);
                rb0 = *(const int4*)(pb + kt + 64);
            }
        }
        __syncthreads();
        p ^= 1;
    }

#pragma unroll
    for (int mi = 0; mi < 4; mi++)
#pragma unroll
        for (int nj = 0; nj < 4; nj++)
#pragma unroll
            for (int r = 0; r < 4; r++) {
                int row = m0 + wr * 64 + mi * 16 + l4 * 4 + r;
                int col = n0 + wc * 64 + nj * 16 + l15;
                float v = acc[mi][nj][r];
                if constexpr (EPI == 0) {
                    outb[(size_t)row * N + col] = f2bf(v);
                } else if constexpr (EPI == 1) {
                    fout[(size_t)row * N + col] = v + bias[col];
                } else if constexpr (EPI == 6) {
                    outb[(size_t)row * N + col] = f2bf(v + bias[col]);
                } else if constexpr (EPI == 7) {
                    size_t idx = (size_t)row * N + col;
                    v += bias[col] + bf2f(outb[idx]);
                    outb[idx] = f2bf(v);
                } else if constexpr (EPI == 8) {
                    size_t idx = (size_t)(col >> 9) * 8388608 + (size_t)row * 512 + (col & 511);
                    outb[idx] = f2bf(v);
                }
            }
}

// ---------------- GEGLU MFMA: 256x64(x2 halves) tile, 8 waves, fused exact GELU --------
// Single-buffer 2-barrier (r31 cherry-pick): geglu runs 2048 blocks and relies on
// multi-block/CU overlap; dbuf's 48KB LDS cut occupancy 36->22 and cost 7us (r30).
__global__ __launch_bounds__(512) void geglu_mfma(const u16* __restrict__ A,
                                                  const u16* __restrict__ WgT,  // [4096][512]
                                                  const float* __restrict__ bg,
                                                  u16* __restrict__ ag) {
    __shared__ u16 As[256 * 32];
    __shared__ u16 Bs1[64 * 32];
    __shared__ u16 Bs2[64 * 32];
    const int K = 512;
    int tid = threadIdx.x;
    int m0 = blockIdx.y * 256, n0 = blockIdx.x * 64;
    int wave = tid >> 6, lane = tid & 63;
    int wr = wave >> 1, wc = wave & 1;
    int l15 = lane & 15, l4 = lane >> 4;

    f32x4 zero4 = {0.f, 0.f, 0.f, 0.f};
    f32x4 accA[4][2], accG[4][2];
#pragma unroll
    for (int i = 0; i < 4; i++) { accA[i][0] = zero4; accA[i][1] = zero4; accG[i][0] = zero4; accG[i][1] = zero4; }

    int srow = tid >> 1;
    int sc0  = (tid & 1) * 2;
    int se   = sc0 * 8;
    int bsel = tid >> 8;
    int bt   = tid & 255;
    int brow = bt >> 2;
    int bch  = bt & 3;
    int bqe  = bch * 8;
    const u16* gbp = WgT + (size_t)(bsel * 2048 + n0 + brow) * K + bqe;

    int4 ra0, ra1, rb;
    {
        const u16* pa = A + (size_t)(m0 + srow) * K + se;
        ra0 = *(const int4*)pa; ra1 = *(const int4*)(pa + 8);
        rb = *(const int4*)gbp;
    }
    for (int kt = 0; kt < K; kt += 32) {
        __syncthreads();
        *(int4*)&As[swzg(srow, sc0)]     = ra0;
        *(int4*)&As[swzg(srow, sc0 + 1)] = ra1;
        if (bsel == 0) *(int4*)&Bs1[swzg(brow, bch)] = rb;
        else           *(int4*)&Bs2[swzg(brow, bch)] = rb;
        __syncthreads();
        int kn = kt + 32;
        if (kn < K) {
            const u16* pa = A + (size_t)(m0 + srow) * K + kn + se;
            ra0 = *(const int4*)pa; ra1 = *(const int4*)(pa + 8);
            rb = *(const int4*)(gbp + kn);
        }
        bf16x8 af[4], b1[2], b2[2];
#pragma unroll
        for (int mi = 0; mi < 4; mi++)
            af[mi] = *(const bf16x8*)&As[swzg(wr * 64 + mi * 16 + l15, l4)];
#pragma unroll
        for (int nj = 0; nj < 2; nj++) {
            b1[nj] = *(const bf16x8*)&Bs1[swzg(wc * 32 + nj * 16 + l15, l4)];
            b2[nj] = *(const bf16x8*)&Bs2[swzg(wc * 32 + nj * 16 + l15, l4)];
        }
#pragma unroll
        for (int mi = 0; mi < 4; mi++)
#pragma unroll
            for (int nj = 0; nj < 2; nj++) {
                accA[mi][nj] = __builtin_amdgcn_mfma_f32_16x16x32_bf16(af[mi], b1[nj], accA[mi][nj], 0, 0, 0);
                accG[mi][nj] = __builtin_amdgcn_mfma_f32_16x16x32_bf16(af[mi], b2[nj], accG[mi][nj], 0, 0, 0);
            }
    }

#pragma unroll
    for (int mi = 0; mi < 4; mi++)
#pragma unroll
        for (int nj = 0; nj < 2; nj++)
#pragma unroll
            for (int r = 0; r < 4; r++) {
                int row = m0 + wr * 64 + mi * 16 + l4 * 4 + r;
                int col = n0 + wc * 32 + nj * 16 + l15;
                float a = accA[mi][nj][r] + bg[col];
                float g = accG[mi][nj][r] + bg[2048 + col];
                ag[(size_t)row * 2048 + col] = f2bf(a * gelu_f(g));
            }
}

// ---------------- MFMA flash attention: QBLK=128, KVBLK=128, reg-prefetched staging ----
// Grid roles: x = h (fastest), y = q-block -> K/V-sharing blocks on same XCD (L2 reuse).
// T13 defer-max (r35, kept): skip O-rescale while growth <= THR.
__global__ __launch_bounds__(512) void flash_attn_mfma(const u16* __restrict__ q,
                                                       const u16* __restrict__ k,
                                                       const u16* __restrict__ vt,  // [b*8+h][64][1024]
                                                       u16* __restrict__ o) {
    __shared__ u16 Ps[2 * 128 * 64];
    __shared__ u16 Ks[128 * 64];
    __shared__ u16 Vt[2 * 64 * 64];
    const int tid = threadIdx.x;
    const int h = blockIdx.x, b = blockIdx.z;
    const int q0 = blockIdx.y * 128;
    const size_t hb  = (size_t)b * Ss * Cch + (size_t)h * DHh;
    const size_t vhb = ((size_t)(b * NHh + h) * DHh) * Ss;

    const int wq = tid >> 6;               // 0..7: wave owns q-rows wq*16..wq*16+15
    const int lane = tid & 63;
    const int l15 = lane & 15, l4 = lane >> 4;

    // staging thread maps (fixed per thread)
    const int kr = tid >> 2, kc = (tid & 3) * 2;           // K: row, chunk pair
    const int vf = tid >> 8, vtn = tid & 255;              // V: half, thread-in-half
    const int vd = vtn >> 2, vc = (vtn & 3) * 2;           // V: row, chunk pair
    const u16* kbase = k + hb + (size_t)kr * Cch + (size_t)kc * 8;
    const u16* vbase = vt + vhb + (size_t)vd * Ss + vf * 64 + (size_t)vc * 8;

    // stage Q (128x64) into Ps half 0 (chunks 0..7)
    {
        int r = tid >> 2, ch = (tid & 3) * 2;
        const u16* src = q + hb + (size_t)(q0 + r) * Cch;
        *(int4*)&Ps[psw(r, ch)]     = *(const int4*)(src + ch * 8);
        *(int4*)&Ps[psw(r, ch + 1)] = *(const int4*)(src + (ch + 1) * 8);
    }
    __syncthreads();
    bf16x8 aq[2];
    aq[0] = *(const bf16x8*)&Ps[psw(wq * 16 + l15, 0 * 4 + l4)];
    aq[1] = *(const bf16x8*)&Ps[psw(wq * 16 + l15, 1 * 4 + l4)];

    f32x4 zero4 = {0.f, 0.f, 0.f, 0.f};
    f32x4 oacc[4];
    float m_[4], l_[4];
#pragma unroll
    for (int j = 0; j < 4; j++) oacc[j] = zero4;
#pragma unroll
    for (int r = 0; r < 4; r++) { m_[r] = -1e30f; l_[r] = 0.f; }

    // prologue: load tile 0's K/V into registers
    int4 rk0, rk1, rv0, rv1;
    rk0 = *(const int4*)(kbase);
    rk1 = *(const int4*)(kbase + 8);
    rv0 = *(const int4*)(vbase);
    rv1 = *(const int4*)(vbase + 8);

    for (int t0 = 0; t0 < Ss; t0 += 128) {
        __syncthreads();                           // prev tile's LDS reads done
        *(int4*)&Ks[swz(kr, kc)]     = rk0;
        *(int4*)&Ks[swz(kr, kc + 1)] = rk1;
        *(int4*)&Vt[vsw(vd, vf * 8 + vc)]     = rv0;
        *(int4*)&Vt[vsw(vd, vf * 8 + vc + 1)] = rv1;
        __syncthreads();                           // tile ready
        if (t0 + 128 < Ss) {
            rk0 = *(const int4*)(kbase + (size_t)(t0 + 128) * Cch);
            rk1 = *(const int4*)(kbase + (size_t)(t0 + 128) * Cch + 8);
            rv0 = *(const int4*)(vbase + t0 + 128);
            rv1 = *(const int4*)(vbase + t0 + 128 + 8);
        }

        // QK^T (log2-scaled): wave's 16 q-rows x 128 t-cols
        f32x4 sacc[8];
#pragma unroll
        for (int j = 0; j < 8; j++) sacc[j] = zero4;
#pragma unroll
        for (int ks = 0; ks < 2; ks++) {
#pragma unroll
            for (int j = 0; j < 8; j++) {
                bf16x8 bk = *(const bf16x8*)&Ks[swz(j * 16 + l15, ks * 4 + l4)];
                sacc[j] = __builtin_amdgcn_mfma_f32_16x16x32_bf16(aq[ks], bk, sacc[j], 0, 0, 0);
            }
        }

        float tmv[4];
        int grew = 0;
#pragma unroll
        for (int r = 0; r < 4; r++) {
            float tm = fmaxf(fmaxf(fmaxf(sacc[0][r], sacc[1][r]), fmaxf(sacc[2][r], sacc[3][r])),
                             fmaxf(fmaxf(sacc[4][r], sacc[5][r]), fmaxf(sacc[6][r], sacc[7][r])));
            tm = fmaxf(tm, __shfl_xor(tm, 1));
            tm = fmaxf(tm, __shfl_xor(tm, 2));
            tm = fmaxf(tm, __shfl_xor(tm, 4));
            tm = fmaxf(tm, __shfl_xor(tm, 8));
            tmv[r] = tm;
            grew |= (tm > m_[r] + DEFER_THR);      // T13: tolerate growth <= THR
        }

        if (__any(grew)) {
#pragma unroll
            for (int r = 0; r < 4; r++) {
                float nm = fmaxf(m_[r], tmv[r]);
                float sc = exp2_raw(m_[r] - nm);
                m_[r] = nm;
                int row = wq * 16 + l4 * 4 + r;
                int rx = row & 7, b64 = row * 64, wi = l15 & 7, hi = l15 >> 3;
                float rs = 0.f;
#pragma unroll
                for (int j = 0; j < 8; j++) {
                    float p = exp2_raw(sacc[j][r] - nm);
                    int cnk = 2 * j + hi;
                    Ps[((cnk >> 3) << 13) + b64 + (((cnk & 7) ^ rx) * 8) + wi] = f2bf_rz(p);
                    rs += p;
                }
                l_[r] = l_[r] * sc + rs;
#pragma unroll
                for (int j = 0; j < 4; j++) oacc[j][r] *= sc;
            }
        } else {
#pragma unroll
            for (int r = 0; r < 4; r++) {
                float nm = m_[r];
                int row = wq * 16 + l4 * 4 + r;
                int rx = row & 7, b64 = row * 64, wi = l15 & 7, hi = l15 >> 3;
                float rs = 0.f;
#pragma unroll
                for (int j = 0; j < 8; j++) {
                    float p = exp2_raw(sacc[j][r] - nm);
                    int cnk = 2 * j + hi;
                    Ps[((cnk >> 3) << 13) + b64 + (((cnk & 7) ^ rx) * 8) + wi] = f2bf_rz(p);
                    rs += p;
                }
                l_[r] += rs;
            }
        }

        // PV: A=Ps (wave-private rows, k=128 -> 4 ks), Bt=Vt[d][t]
#pragma unroll
        for (int ks = 0; ks < 4; ks++) {
            bf16x8 pa = *(const bf16x8*)&Ps[psw(wq * 16 + l15, ks * 4 + l4)];
#pragma unroll
            for (int j = 0; j < 4; j++) {
                bf16x8 bv = *(const bf16x8*)&Vt[vsw(j * 16 + l15, ks * 4 + l4)];
                oacc[j] = __builtin_amdgcn_mfma_f32_16x16x32_bf16(pa, bv, oacc[j], 0, 0, 0);
            }
        }
    }

    // finalize: reduce per-lane l partials, O /= l, stage via Ps half 0, coalesced store
#pragma unroll
    for (int r = 0; r < 4; r++) {
        float lt = l_[r];
        lt += __shfl_xor(lt, 1);
        lt += __shfl_xor(lt, 2);
        lt += __shfl_xor(lt, 4);
        lt += __shfl_xor(lt, 8);
        float inv = 1.0f / lt;
        int row = wq * 16 + l4 * 4 + r;
        int rx = row & 7, b64 = row * 64, wi = l15 & 7, hi = l15 >> 3;
#pragma unroll
        for (int j = 0; j < 4; j++) {
            int cnk = 2 * j + hi;    // 0..7 (half 0)
            Ps[b64 + ((cnk ^ rx) * 8) + wi] = f2bf(oacc[j][r] * inv);
        }
    }
    __syncthreads();
    {
        int r = tid >> 2, ch = (tid & 3) * 2;
        u16* dst = o + hb + (size_t)(q0 + r) * Cch;
        *(int4*)(dst + ch * 8)       = *(const int4*)&Ps[psw(r, ch)];
        *(int4*)(dst + (ch + 1) * 8) = *(const int4*)&Ps[psw(r, ch + 1)];
    }
}

// ---------------- final: out(B,C,S) = tmp(B,S,C bf16)^T + x ----------------
__global__ __launch_bounds__(256) void final_out_bf(const u16* __restrict__ tmp,
                                                    const float* __restrict__ x,
                                                    float* __restrict__ outp) {
    __shared__ float tile[32][33];
    int b = blockIdx.z, c0 = blockIdx.y * 32, s0 = blockIdx.x * 32;
    int tx = threadIdx.x, ty = threadIdx.y;
#pragma unroll
    for (int i = 0; i < 4; i++) {
        int s = s0 + ty + i * 8;
        tile[ty + i * 8][tx] = bf2f(tmp[((size_t)b * Ss + s) * Cch + c0 + tx]);
    }
    __syncthreads();
#pragma unroll
    for (int i = 0; i < 4; i++) {
        int c = c0 + ty + i * 8;
        size_t idx = ((size_t)b * Cch + c) * Ss + s0 + tx;
        outp[idx] = tile[tx][ty + i * 8] + x[idx];
    }
}

extern "C" void kernel_launch(void* const* d_in, const int* in_sizes, int n_in,
                              void* d_out, int out_size, void* d_ws, size_t ws_size,
                              hipStream_t stream) {
    (void)in_sizes; (void)n_in; (void)out_size; (void)ws_size;
    const float* x      = (const float*)d_in[0];
    const float* gn_w   = (const float*)d_in[1];
    const float* gn_b   = (const float*)d_in[2];
    const float* pin_w  = (const float*)d_in[3];
    const float* pin_b  = (const float*)d_in[4];
    const float* ln1_w  = (const float*)d_in[5];
    const float* ln1_b  = (const float*)d_in[6];
    const float* wq     = (const float*)d_in[7];
    const float* wk     = (const float*)d_in[8];
    const float* wv     = (const float*)d_in[9];
    const float* wo     = (const float*)d_in[10];
    const float* bo     = (const float*)d_in[11];
    const float* ln3_w  = (const float*)d_in[12];
    const float* ln3_b  = (const float*)d_in[13];
    const float* wg     = (const float*)d_in[14];
    const float* bg     = (const float*)d_in[15];
    const float* wd     = (const float*)d_in[16];
    const float* bd     = (const float*)d_in[17];
    const float* pout_w = (const float*)d_in[18];
    const float* pout_b = (const float*)d_in[19];
    float* out = (float*)d_out;

    // ---- workspace layout (bytes) ----
    char* W = (char*)d_ws;
    u16* tb        = (u16*)W;                                     // t residual, bf16, 16.78 MB
    float* tmp_f32 = (float*)(W + 33554432);                      // vtb region
    u16* qb    = (u16*)(W + 67108864);                            // 16.78 MB (qb,kb,vb contiguous)
    u16* kb    = qb + 8388608;
    u16* vb    = kb + 8388608;
    u16* attnb = vb + 8388608;
    u16* Xb    = attnb + 8388608;                                 // 16.78 MB
    float* stats = (float*)(W + 67108864 + 5ull * 16777216);      // 2 KB (256 partial pairs)
    u16* wbase = (u16*)(W + 67108864 + 5ull * 16777216 + 2048);
    u16* pinB  = wbase;                 // 512*512  (already [N][K])
    u16* poutB = pinB  + 262144;
    u16* wqT   = poutB + 262144;        // [512][512] transposed, scaled by QSCL
    u16* wkT   = wqT   + 262144;        // contiguous with wqT -> [1536][512] for fused qkv
    u16* wvT   = wkT   + 262144;
    u16* woT   = wvT   + 262144;
    u16* wgT   = woT   + 262144;        // [4096][512]
    u16* wdT   = wgT   + 2097152;       // [512][2048]
    u16* ag    = qb;                    // R x 2048 bf16, aliases qb..attnb (dead by then)
    u16* vtb   = (u16*)tmp_f32;         // V^T [b*8+h][64][1024]

    dim3 tb8(32, 8);

    // partial stats (256 blocks, full machine) + fused weight prep
    gn_stats<<<256, 256, 0, stream>>>(x, stats);
    prep_all<<<4608, tb8, 0, stream>>>(pin_w, pout_w, pinB, poutB,
                                       wq, wk, wv, wo, wqT, wkT, wvT, woT,
                                       wg, wgT, wd, wdT);

    // h = GN(x) transposed -> Xb (bf16); combines stat partials
    gn_apply_t_bf<<<dim3(32, 16, 16), tb8, 0, stream>>>(x, stats, gn_w, gn_b, Xb);

    // t = h @ pin_w^T + pin_b -> tb (bf16)
    mfma_gemm<6><<<dim3(4, 64), 512, 0, stream>>>(Xb, pinB, pin_b, nullptr, tb, 512, 512);
    // tn = ln1(t) -> Xb
    layer_norm_rows_bf<<<4096, 256, 0, stream>>>(tb, ln1_w, ln1_b, Xb);
    // fused q(scaled)/k/v: N=1536, routed to qb/kb/vb
    mfma_gemm<8><<<dim3(12, 64), 512, 0, stream>>>(Xb, wqT, nullptr, nullptr, qb, 512, 1536);
    // per-head V transpose -> vtb
    vtrans<<<dim3(16, 8, 16), 256, 0, stream>>>(vb, vtb);
    // attention (MFMA, QBLK=128, KVBLK=128, prefetched, defer-max) -> attnb
    flash_attn_mfma<<<dim3(8, 8, 16), 512, 0, stream>>>(qb, kb, vtb, attnb);
    // t += attn @ wo + bo (bf16 in-place on tb)
    mfma_gemm<7><<<dim3(4, 64), 512, 0, stream>>>(attnb, woT, bo, nullptr, tb, 512, 512);
    // tn3 = ln3(t) -> Xb
    layer_norm_rows_bf<<<4096, 256, 0, stream>>>(tb, ln3_w, ln3_b, Xb);
    // ag = a * gelu(g) (bf16), aliases q/k/v/attn space
    geglu_mfma<<<dim3(32, 64), 512, 0, stream>>>(Xb, wgT, bg, ag);
    // t += ag @ wd + bd (bf16 in-place on tb)
    mfma_gemm<7><<<dim3(4, 64), 512, 0, stream>>>(ag, wdT, bd, nullptr, tb, 2048, 512);
    // tmp = t @ pout_w^T + pout_b -> Xb (bf16)
    mfma_gemm<6><<<dim3(4, 64), 512, 0, stream>>>(tb, poutB, pout_b, nullptr, Xb, 512, 512);
    // out = tmp^T + x
    final_out_bf<<<dim3(32, 16, 16), tb8, 0, stream>>>(Xb, x, out);
}

// Round 38
// 380.214 us; speedup vs baseline: 1.0702x; 1.0072x over previous
//
#include <hip/hip_runtime.h>
#include <hip/hip_bf16.h>
#include <math.h>

typedef unsigned short u16;
typedef __attribute__((ext_vector_type(8))) short bf16x8;
typedef __attribute__((ext_vector_type(4))) float f32x4;

#define Bb 16
#define Cch 512
#define Ss 1024
#define NHh 8
#define DHh 64
#define CPG 64
#define EPSV 1e-5f
#define R_TOTAL (Bb*Ss)   // 16384
#define QSCL 0.18033688011112042f   // 0.125 * log2(e)
#define DEFER_THR 8.0f    // T13: skip O-rescale while tile-max growth <= 8 (log2 domain)

__device__ inline u16 f2bf(float f) {
    unsigned int u = __float_as_uint(f);
    unsigned int r = (u + 0x7fffu + ((u >> 16) & 1u)) >> 16;
    return (u16)r;
}
__device__ inline u16 f2bf_rz(float f) { return (u16)(__float_as_uint(f) >> 16); }
__device__ inline float bf2f(u16 v) { return __uint_as_float((unsigned)v << 16); }
__device__ inline float exp2_raw(float x) {
    float r; asm("v_exp_f32 %0, %1" : "=v"(r) : "v"(x)); return r;
}
__device__ inline float rcp_raw(float x) {
    float r; asm("v_rcp_f32 %0, %1" : "=v"(r) : "v"(x)); return r;
}
// branchless exact-GELU via Abramowitz-Stegun 7.1.26 erf (max err 1.5e-7)
__device__ inline float gelu_f(float g) {
    float z = fabsf(g) * 0.70710678118654752f;
    float t = rcp_raw(1.0f + 0.3275911f * z);
    float poly = t * (0.254829592f + t * (-0.284496736f + t * (1.421413741f +
                 t * (-1.453152027f + t * 1.061405429f))));
    float e = exp2_raw(-z * z * 1.44269504089f);
    float erfa = 1.0f - poly * e;
    float erfv = (g < 0.f) ? -erfa : erfa;
    return 0.5f * g * (1.0f + erfv);
}

// swizzles: 16B chunk XOR'd by row&7 within stride-64 rows (proven clean r14-r25).
__device__ inline int swz(int row, int chunk) {      // [R][64] tile
    return row * 64 + ((chunk ^ (row & 7)) * 8);
}
// 128-wide tiles split into two stride-64 halves (chunk bit 3 = half select, wave-uniform)
__device__ inline int psw(int row, int chunk) {      // Ps[128][128]: halves of [128][64]
    return ((chunk >> 3) << 13) + row * 64 + (((chunk & 7) ^ (row & 7)) * 8);
}
__device__ inline int vsw(int row, int chunk) {      // Vt[64][128]: halves of [64][64]
    return ((chunk >> 3) << 12) + row * 64 + (((chunk & 7) ^ (row & 7)) * 8);
}
__device__ inline int swzg(int r, int c) {           // GEMM [R][32] tile
    int span = r >> 1;
    int c8 = ((r & 1) << 2) | c;
    return span * 64 + ((c8 ^ (span & 7)) * 8);
}

// ---------------- fused prep: GroupNorm partial stats + ALL weight prep (r38) ----------
// Stats blocks (first 256) and weight-prep blocks (4608) are independent; merging them
// into one launch lets them co-schedule instead of serializing on the stream.
__global__ __launch_bounds__(256) void prep_all(const float* __restrict__ x,
                                                float* __restrict__ pstats,
                                                const float* __restrict__ pin_w,
                                                const float* __restrict__ pout_w,
                                                u16* __restrict__ pinB,
                                                u16* __restrict__ poutB,
                                                const float* __restrict__ wq,
                                                const float* __restrict__ wk,
                                                const float* __restrict__ wv,
                                                const float* __restrict__ wo,
                                                u16* __restrict__ wqT,
                                                u16* __restrict__ wkT,
                                                u16* __restrict__ wvT,
                                                u16* __restrict__ woT,
                                                const float* __restrict__ wg,
                                                u16* __restrict__ wgT,
                                                const float* __restrict__ wd,
                                                u16* __restrict__ wdT) {
    __shared__ float tile[32][33];
    int tx = threadIdx.x, ty = threadIdx.y;
    int tid = ty * 32 + tx;
    if (blockIdx.x < 256) {
        // --- GroupNorm partial stats: 2 half-blocks per (b,g) ---
        int bgh = blockIdx.x;            // (b*8+g)*2 + half
        int bg = bgh >> 1, half = bgh & 1;
        int b = bg >> 3, g = bg & 7;
        const float4* base = (const float4*)(x + ((size_t)b * Cch + (size_t)g * CPG) * Ss)
                             + (size_t)half * (CPG * Ss / 8);
        float s = 0.f, ss = 0.f;
        for (int i = tid; i < CPG * Ss / 8; i += 256) {
            float4 v = base[i];
            s  += v.x + v.y + v.z + v.w;
            ss += v.x * v.x + v.y * v.y + v.z * v.z + v.w * v.w;
        }
        for (int o = 32; o > 0; o >>= 1) { s += __shfl_down(s, o); ss += __shfl_down(ss, o); }
        __shared__ float red[2][4];
        int wid = tid >> 6, lane = tid & 63;
        if (lane == 0) { red[0][wid] = s; red[1][wid] = ss; }
        __syncthreads();
        if (tid == 0) {
            pstats[bgh * 2]     = red[0][0] + red[0][1] + red[0][2] + red[0][3];
            pstats[bgh * 2 + 1] = red[1][0] + red[1][1] + red[1][2] + red[1][3];
        }
        return;
    }
    int bid = blockIdx.x - 256;
    if (bid < 512) {
        int base = bid * 1024 + tid * 4;
        const float* src; u16* dst; int off;
        if (base < 262144) { src = pin_w;  dst = pinB;  off = base; }
        else               { src = pout_w; dst = poutB; off = base - 262144; }
        float4 v = *(const float4*)&src[off];
        ushort4 o;
        o.x = f2bf(v.x); o.y = f2bf(v.y); o.z = f2bf(v.z); o.w = f2bf(v.w);
        *(ushort4*)&dst[off] = o;
        return;
    }
    const float* in; u16* outp; int c0, r0, C, R; float scl = 1.0f;
    if (bid < 1536) {
        int z = (bid - 512) >> 8, rem = (bid - 512) & 255;
        switch (z) {
            case 0: in = wq; outp = wqT; scl = QSCL; break;
            case 1: in = wk; outp = wkT; break;
            case 2: in = wv; outp = wvT; break;
            default: in = wo; outp = woT; break;
        }
        c0 = (rem & 15) * 32; r0 = (rem >> 4) * 32; C = 512; R = 512;
    } else if (bid < 3584) {
        int rem = bid - 1536;
        in = wg; outp = wgT; C = 4096; R = 512;
        c0 = (rem & 127) * 32; r0 = (rem >> 7) * 32;
    } else {
        int rem = bid - 3584;
        in = wd; outp = wdT; C = 512; R = 2048;
        c0 = (rem & 15) * 32; r0 = (rem >> 4) * 32;
    }
#pragma unroll
    for (int i = 0; i < 4; i++)
        tile[ty + i * 8][tx] = in[(size_t)(r0 + ty + i * 8) * C + c0 + tx] * scl;
    __syncthreads();
#pragma unroll
    for (int i = 0; i < 4; i++)
        outp[(size_t)(c0 + ty + i * 8) * R + r0 + tx] = f2bf(tile[tx][ty + i * 8]);
}

// ---------------- GroupNorm apply + transpose -> bf16 (B,S,C); combines partials ------
__global__ __launch_bounds__(256) void gn_apply_t_bf(const float* __restrict__ x,
                                                     const float* __restrict__ pstats,
                                                     const float* __restrict__ gw,
                                                     const float* __restrict__ gb,
                                                     u16* __restrict__ ht) {
    __shared__ float tile[32][33];
    int b  = blockIdx.z;
    int c0 = blockIdx.y * 32;
    int s0 = blockIdx.x * 32;
    int tx = threadIdx.x, ty = threadIdx.y;
    const float inv_n = 1.0f / (CPG * Ss);
#pragma unroll
    for (int i = 0; i < 4; i++) {
        int c = c0 + ty + i * 8;
        int g = c >> 6;
        int bg = b * 8 + g;
        float S1 = pstats[(bg * 2) * 2]     + pstats[(bg * 2 + 1) * 2];
        float S2 = pstats[(bg * 2) * 2 + 1] + pstats[(bg * 2 + 1) * 2 + 1];
        float mu = S1 * inv_n;
        float var = S2 * inv_n - mu * mu;
        float rs = rsqrtf(var + EPSV);
        float v = x[((size_t)b * Cch + c) * Ss + s0 + tx];
        tile[ty + i * 8][tx] = (v - mu) * rs * gw[c] + gb[c];
    }
    __syncthreads();
#pragma unroll
    for (int i = 0; i < 4; i++) {
        int s = s0 + ty + i * 8;
        ht[((size_t)b * Ss + s) * Cch + c0 + tx] = f2bf(tile[tx][ty + i * 8]);
    }
}

// ---------------- per-head V transpose: vb [b][s][512] -> vt [(b*8+h)][64][1024] ----------
__global__ __launch_bounds__(256) void vtrans(const u16* __restrict__ in,
                                              u16* __restrict__ outp) {
    __shared__ u16 tile[64][66];
    int s0 = blockIdx.x * 64, h = blockIdx.y, b = blockIdx.z;
    const u16* src = in + ((size_t)b * Ss + s0) * Cch + h * 64;
    int r = threadIdx.x >> 3, c8 = (threadIdx.x & 7) * 8;
#pragma unroll
    for (int p = 0; p < 2; p++) {
        int rr = r + p * 32;
        *(int4*)&tile[rr][c8] = *(const int4*)&src[(size_t)rr * Cch + c8];
    }
    __syncthreads();
    u16* dst = outp + ((size_t)(b * 8 + h) * 64) * Ss + s0;
#pragma unroll
    for (int p = 0; p < 2; p++) {
        int d = r + p * 32;
        u16 vals[8];
#pragma unroll
        for (int e = 0; e < 8; e++) vals[e] = tile[c8 + e][d];
        *(int4*)&dst[(size_t)d * Ss + c8] = *(int4*)vals;
    }
}

// ---------------- LayerNorm rows: 1 wave per row, 4 rows/block (r37 win) --------------
__global__ __launch_bounds__(256) void layer_norm_rows_bf(const u16* __restrict__ in,
                                                          const float* __restrict__ w,
                                                          const float* __restrict__ bb,
                                                          u16* __restrict__ outp) {
    int row  = blockIdx.x * 4 + (threadIdx.x >> 6);
    int lane = threadIdx.x & 63;
    int i0   = lane * 8;
    const u16* p = in + (size_t)row * Cch + i0;
    int4 v = *(const int4*)p;
    u16 us[8];
    *(int4*)us = v;
    float f[8];
    float s = 0.f, ss = 0.f;
#pragma unroll
    for (int e = 0; e < 8; e++) {
        f[e] = bf2f(us[e]);
        s += f[e];
        ss += f[e] * f[e];
    }
#pragma unroll
    for (int o = 32; o > 0; o >>= 1) {
        s  += __shfl_xor(s, o);
        ss += __shfl_xor(ss, o);
    }
    float mu = s * (1.0f / Cch);
    float var = ss * (1.0f / Cch) - mu * mu;
    float rs = rsqrtf(var + EPSV);
    float4 w0 = *(const float4*)&w[i0];
    float4 w1 = *(const float4*)&w[i0 + 4];
    float4 b0 = *(const float4*)&bb[i0];
    float4 b1 = *(const float4*)&bb[i0 + 4];
    float wv[8] = {w0.x, w0.y, w0.z, w0.w, w1.x, w1.y, w1.z, w1.w};
    float bv[8] = {b0.x, b0.y, b0.z, b0.w, b1.x, b1.y, b1.z, b1.w};
    u16 o8[8];
#pragma unroll
    for (int e = 0; e < 8; e++)
        o8[e] = f2bf((f[e] - mu) * rs * wv[e] + bv[e]);
    *(int4*)&outp[(size_t)row * Cch + i0] = *(int4*)o8;
}

// ---------------- MFMA GEMM: out(MxN) = A(MxK bf16) @ Bt(NxK bf16)^T ----------------
// 256x128 tile, BK=32, 512 thr = 8 waves (4x2). Per-wave 64x64; swizzled LDS (swzg).
// DOUBLE-BUFFERED reg staging, 1 barrier per K-step (r30/r31 proven best).
// Dead ends: r28 BK=64 (spill), r32 depth-2, r34 gload_lds, r36 128x128 tile.
// EPI: 0 = bf16; 1 = fp32 +bias; 6 = bf16 +bias; 7 = bf16 +bias + bf16 residual in-place;
//      8 = bf16 routed qkv (outb base = qb; col>>9 selects q/k/v slot, 8388608 apart).
template<int EPI>
__global__ __launch_bounds__(512) void mfma_gemm(const u16* __restrict__ A,
                                                 const u16* __restrict__ Bt,
                                                 const float* __restrict__ bias,
                                                 float* __restrict__ fout,
                                                 u16* __restrict__ outb,
                                                 int K, int N) {
    __shared__ u16 As[2][256 * 32];
    __shared__ u16 Bs[2][128 * 32];
    int tid = threadIdx.x;
    int m0 = blockIdx.y * 256, n0 = blockIdx.x * 128;
    int wave = tid >> 6, lane = tid & 63;
    int wr = wave >> 1, wc = wave & 1;      // 4x2 wave grid
    int l15 = lane & 15, l4 = lane >> 4;

    f32x4 zero4 = {0.f, 0.f, 0.f, 0.f};
    f32x4 acc[4][4];
#pragma unroll
    for (int i = 0; i < 4; i++)
#pragma unroll
        for (int j = 0; j < 4; j++) acc[i][j] = zero4;

    int srow = tid >> 1;
    int sc0  = (tid & 1) * 2;
    int se   = sc0 * 8;
    int brow = tid >> 2;
    int bch  = tid & 3;
    int bqe  = bch * 8;

    const u16* pa = A  + (size_t)(m0 + srow) * K + se;
    const u16* pb = Bt + (size_t)(n0 + brow) * K + bqe;

    // prologue: tile 0 -> buf 0; issue tile 1 loads (K >= 64 always here)
    int4 ra0 = *(const int4*)pa;
    int4 ra1 = *(const int4*)(pa + 8);
    int4 rb0 = *(const int4*)pb;
    *(int4*)&As[0][swzg(srow, sc0)]     = ra0;
    *(int4*)&As[0][swzg(srow, sc0 + 1)] = ra1;
    *(int4*)&Bs[0][swzg(brow, bch)]     = rb0;
    ra0 = *(const int4*)(pa + 32);
    ra1 = *(const int4*)(pa + 40);
    rb0 = *(const int4*)(pb + 32);
    __syncthreads();

    int p = 0;
    for (int kt = 0; kt < K; kt += 32) {
        bf16x8 af[4], bfr[4];
#pragma unroll
        for (int mi = 0; mi < 4; mi++)
            af[mi] = *(const bf16x8*)&As[p][swzg(wr * 64 + mi * 16 + l15, l4)];
#pragma unroll
        for (int nj = 0; nj < 4; nj++)
            bfr[nj] = *(const bf16x8*)&Bs[p][swzg(wc * 64 + nj * 16 + l15, l4)];
#pragma unroll
        for (int mi = 0; mi < 4; mi++)
#pragma unroll
            for (int nj = 0; nj < 4; nj++)
                acc[mi][nj] = __builtin_amdgcn_mfma_f32_16x16x32_bf16(af[mi], bfr[nj], acc[mi][nj], 0, 0, 0);
        if (kt + 32 < K) {
            *(int4*)&As[p ^ 1][swzg(srow, sc0)]     = ra0;
            *(int4*)&As[p ^ 1][swzg(srow, sc0 + 1)] = ra1;
            *(int4*)&Bs[p ^ 1][swzg(brow, bch)]     = rb0;
            if (kt + 64 < K) {
                ra0 = *(const int4*)(pa + kt + 64);
                ra1 = *(const int4*)(pa + kt + 72);
                rb0 = *(const int4*)(pb + kt + 64);
            }
        }
        __syncthreads();
        p ^= 1;
    }

#pragma unroll
    for (int mi = 0; mi < 4; mi++)
#pragma unroll
        for (int nj = 0; nj < 4; nj++)
#pragma unroll
            for (int r = 0; r < 4; r++) {
                int row = m0 + wr * 64 + mi * 16 + l4 * 4 + r;
                int col = n0 + wc * 64 + nj * 16 + l15;
                float v = acc[mi][nj][r];
                if constexpr (EPI == 0) {
                    outb[(size_t)row * N + col] = f2bf(v);
                } else if constexpr (EPI == 1) {
                    fout[(size_t)row * N + col] = v + bias[col];
                } else if constexpr (EPI == 6) {
                    outb[(size_t)row * N + col] = f2bf(v + bias[col]);
                } else if constexpr (EPI == 7) {
                    size_t idx = (size_t)row * N + col;
                    v += bias[col] + bf2f(outb[idx]);
                    outb[idx] = f2bf(v);
                } else if constexpr (EPI == 8) {
                    size_t idx = (size_t)(col >> 9) * 8388608 + (size_t)row * 512 + (col & 511);
                    outb[idx] = f2bf(v);
                }
            }
}

// ---------------- GEGLU MFMA: 256x64(x2 halves) tile, 8 waves, fused exact GELU --------
// Single-buffer 2-barrier (r31 cherry-pick): geglu runs 2048 blocks and relies on
// multi-block/CU overlap; dbuf's 48KB LDS cut occupancy 36->22 and cost 7us (r30).
__global__ __launch_bounds__(512) void geglu_mfma(const u16* __restrict__ A,
                                                  const u16* __restrict__ WgT,  // [4096][512]
                                                  const float* __restrict__ bg,
                                                  u16* __restrict__ ag) {
    __shared__ u16 As[256 * 32];
    __shared__ u16 Bs1[64 * 32];
    __shared__ u16 Bs2[64 * 32];
    const int K = 512;
    int tid = threadIdx.x;
    int m0 = blockIdx.y * 256, n0 = blockIdx.x * 64;
    int wave = tid >> 6, lane = tid & 63;
    int wr = wave >> 1, wc = wave & 1;
    int l15 = lane & 15, l4 = lane >> 4;

    f32x4 zero4 = {0.f, 0.f, 0.f, 0.f};
    f32x4 accA[4][2], accG[4][2];
#pragma unroll
    for (int i = 0; i < 4; i++) { accA[i][0] = zero4; accA[i][1] = zero4; accG[i][0] = zero4; accG[i][1] = zero4; }

    int srow = tid >> 1;
    int sc0  = (tid & 1) * 2;
    int se   = sc0 * 8;
    int bsel = tid >> 8;
    int bt   = tid & 255;
    int brow = bt >> 2;
    int bch  = bt & 3;
    int bqe  = bch * 8;
    const u16* gbp = WgT + (size_t)(bsel * 2048 + n0 + brow) * K + bqe;

    int4 ra0, ra1, rb;
    {
        const u16* pa = A + (size_t)(m0 + srow) * K + se;
        ra0 = *(const int4*)pa; ra1 = *(const int4*)(pa + 8);
        rb = *(const int4*)gbp;
    }
    for (int kt = 0; kt < K; kt += 32) {
        __syncthreads();
        *(int4*)&As[swzg(srow, sc0)]     = ra0;
        *(int4*)&As[swzg(srow, sc0 + 1)] = ra1;
        if (bsel == 0) *(int4*)&Bs1[swzg(brow, bch)] = rb;
        else           *(int4*)&Bs2[swzg(brow, bch)] = rb;
        __syncthreads();
        int kn = kt + 32;
        if (kn < K) {
            const u16* pa = A + (size_t)(m0 + srow) * K + kn + se;
            ra0 = *(const int4*)pa; ra1 = *(const int4*)(pa + 8);
            rb = *(const int4*)(gbp + kn);
        }
        bf16x8 af[4], b1[2], b2[2];
#pragma unroll
        for (int mi = 0; mi < 4; mi++)
            af[mi] = *(const bf16x8*)&As[swzg(wr * 64 + mi * 16 + l15, l4)];
#pragma unroll
        for (int nj = 0; nj < 2; nj++) {
            b1[nj] = *(const bf16x8*)&Bs1[swzg(wc * 32 + nj * 16 + l15, l4)];
            b2[nj] = *(const bf16x8*)&Bs2[swzg(wc * 32 + nj * 16 + l15, l4)];
        }
#pragma unroll
        for (int mi = 0; mi < 4; mi++)
#pragma unroll
            for (int nj = 0; nj < 2; nj++) {
                accA[mi][nj] = __builtin_amdgcn_mfma_f32_16x16x32_bf16(af[mi], b1[nj], accA[mi][nj], 0, 0, 0);
                accG[mi][nj] = __builtin_amdgcn_mfma_f32_16x16x32_bf16(af[mi], b2[nj], accG[mi][nj], 0, 0, 0);
            }
    }

#pragma unroll
    for (int mi = 0; mi < 4; mi++)
#pragma unroll
        for (int nj = 0; nj < 2; nj++)
#pragma unroll
            for (int r = 0; r < 4; r++) {
                int row = m0 + wr * 64 + mi * 16 + l4 * 4 + r;
                int col = n0 + wc * 32 + nj * 16 + l15;
                float a = accA[mi][nj][r] + bg[col];
                float g = accG[mi][nj][r] + bg[2048 + col];
                ag[(size_t)row * 2048 + col] = f2bf(a * gelu_f(g));
            }
}

// ---------------- MFMA flash attention: QBLK=128, KVBLK=128, reg-prefetched staging ----
// Grid roles: x = h (fastest), y = q-block -> K/V-sharing blocks on same XCD (L2 reuse).
// T13 defer-max (r35, kept): skip O-rescale while growth <= THR.
__global__ __launch_bounds__(512) void flash_attn_mfma(const u16* __restrict__ q,
                                                       const u16* __restrict__ k,
                                                       const u16* __restrict__ vt,  // [b*8+h][64][1024]
                                                       u16* __restrict__ o) {
    __shared__ u16 Ps[2 * 128 * 64];
    __shared__ u16 Ks[128 * 64];
    __shared__ u16 Vt[2 * 64 * 64];
    const int tid = threadIdx.x;
    const int h = blockIdx.x, b = blockIdx.z;
    const int q0 = blockIdx.y * 128;
    const size_t hb  = (size_t)b * Ss * Cch + (size_t)h * DHh;
    const size_t vhb = ((size_t)(b * NHh + h) * DHh) * Ss;

    const int wq = tid >> 6;               // 0..7: wave owns q-rows wq*16..wq*16+15
    const int lane = tid & 63;
    const int l15 = lane & 15, l4 = lane >> 4;

    // staging thread maps (fixed per thread)
    const int kr = tid >> 2, kc = (tid & 3) * 2;           // K: row, chunk pair
    const int vf = tid >> 8, vtn = tid & 255;              // V: half, thread-in-half
    const int vd = vtn >> 2, vc = (vtn & 3) * 2;           // V: row, chunk pair
    const u16* kbase = k + hb + (size_t)kr * Cch + (size_t)kc * 8;
    const u16* vbase = vt + vhb + (size_t)vd * Ss + vf * 64 + (size_t)vc * 8;

    // stage Q (128x64) into Ps half 0 (chunks 0..7)
    {
        int r = tid >> 2, ch = (tid & 3) * 2;
        const u16* src = q + hb + (size_t)(q0 + r) * Cch;
        *(int4*)&Ps[psw(r, ch)]     = *(const int4*)(src + ch * 8);
        *(int4*)&Ps[psw(r, ch + 1)] = *(const int4*)(src + (ch + 1) * 8);
    }
    __syncthreads();
    bf16x8 aq[2];
    aq[0] = *(const bf16x8*)&Ps[psw(wq * 16 + l15, 0 * 4 + l4)];
    aq[1] = *(const bf16x8*)&Ps[psw(wq * 16 + l15, 1 * 4 + l4)];

    f32x4 zero4 = {0.f, 0.f, 0.f, 0.f};
    f32x4 oacc[4];
    float m_[4], l_[4];
#pragma unroll
    for (int j = 0; j < 4; j++) oacc[j] = zero4;
#pragma unroll
    for (int r = 0; r < 4; r++) { m_[r] = -1e30f; l_[r] = 0.f; }

    // prologue: load tile 0's K/V into registers
    int4 rk0, rk1, rv0, rv1;
    rk0 = *(const int4*)(kbase);
    rk1 = *(const int4*)(kbase + 8);
    rv0 = *(const int4*)(vbase);
    rv1 = *(const int4*)(vbase + 8);

    for (int t0 = 0; t0 < Ss; t0 += 128) {
        __syncthreads();                           // prev tile's LDS reads done
        *(int4*)&Ks[swz(kr, kc)]     = rk0;
        *(int4*)&Ks[swz(kr, kc + 1)] = rk1;
        *(int4*)&Vt[vsw(vd, vf * 8 + vc)]     = rv0;
        *(int4*)&Vt[vsw(vd, vf * 8 + vc + 1)] = rv1;
        __syncthreads();                           // tile ready
        if (t0 + 128 < Ss) {
            rk0 = *(const int4*)(kbase + (size_t)(t0 + 128) * Cch);
            rk1 = *(const int4*)(kbase + (size_t)(t0 + 128) * Cch + 8);
            rv0 = *(const int4*)(vbase + t0 + 128);
            rv1 = *(const int4*)(vbase + t0 + 128 + 8);
        }

        // QK^T (log2-scaled): wave's 16 q-rows x 128 t-cols
        f32x4 sacc[8];
#pragma unroll
        for (int j = 0; j < 8; j++) sacc[j] = zero4;
#pragma unroll
        for (int ks = 0; ks < 2; ks++) {
#pragma unroll
            for (int j = 0; j < 8; j++) {
                bf16x8 bk = *(const bf16x8*)&Ks[swz(j * 16 + l15, ks * 4 + l4)];
                sacc[j] = __builtin_amdgcn_mfma_f32_16x16x32_bf16(aq[ks], bk, sacc[j], 0, 0, 0);
            }
        }

        float tmv[4];
        int grew = 0;
#pragma unroll
        for (int r = 0; r < 4; r++) {
            float tm = fmaxf(fmaxf(fmaxf(sacc[0][r], sacc[1][r]), fmaxf(sacc[2][r], sacc[3][r])),
                             fmaxf(fmaxf(sacc[4][r], sacc[5][r]), fmaxf(sacc[6][r], sacc[7][r])));
            tm = fmaxf(tm, __shfl_xor(tm, 1));
            tm = fmaxf(tm, __shfl_xor(tm, 2));
            tm = fmaxf(tm, __shfl_xor(tm, 4));
            tm = fmaxf(tm, __shfl_xor(tm, 8));
            tmv[r] = tm;
            grew |= (tm > m_[r] + DEFER_THR);      // T13: tolerate growth <= THR
        }

        if (__any(grew)) {
#pragma unroll
            for (int r = 0; r < 4; r++) {
                float nm = fmaxf(m_[r], tmv[r]);
                float sc = exp2_raw(m_[r] - nm);
                m_[r] = nm;
                int row = wq * 16 + l4 * 4 + r;
                int rx = row & 7, b64 = row * 64, wi = l15 & 7, hi = l15 >> 3;
                float rs = 0.f;
#pragma unroll
                for (int j = 0; j < 8; j++) {
                    float p = exp2_raw(sacc[j][r] - nm);
                    int cnk = 2 * j + hi;
                    Ps[((cnk >> 3) << 13) + b64 + (((cnk & 7) ^ rx) * 8) + wi] = f2bf_rz(p);
                    rs += p;
                }
                l_[r] = l_[r] * sc + rs;
#pragma unroll
                for (int j = 0; j < 4; j++) oacc[j][r] *= sc;
            }
        } else {
#pragma unroll
            for (int r = 0; r < 4; r++) {
                float nm = m_[r];
                int row = wq * 16 + l4 * 4 + r;
                int rx = row & 7, b64 = row * 64, wi = l15 & 7, hi = l15 >> 3;
                float rs = 0.f;
#pragma unroll
                for (int j = 0; j < 8; j++) {
                    float p = exp2_raw(sacc[j][r] - nm);
                    int cnk = 2 * j + hi;
                    Ps[((cnk >> 3) << 13) + b64 + (((cnk & 7) ^ rx) * 8) + wi] = f2bf_rz(p);
                    rs += p;
                }
                l_[r] += rs;
            }
        }

        // PV: A=Ps (wave-private rows, k=128 -> 4 ks), Bt=Vt[d][t]
#pragma unroll
        for (int ks = 0; ks < 4; ks++) {
            bf16x8 pa = *(const bf16x8*)&Ps[psw(wq * 16 + l15, ks * 4 + l4)];
#pragma unroll
            for (int j = 0; j < 4; j++) {
                bf16x8 bv = *(const bf16x8*)&Vt[vsw(j * 16 + l15, ks * 4 + l4)];
                oacc[j] = __builtin_amdgcn_mfma_f32_16x16x32_bf16(pa, bv, oacc[j], 0, 0, 0);
            }
        }
    }

    // finalize: reduce per-lane l partials, O /= l, stage via Ps half 0, coalesced store
#pragma unroll
    for (int r = 0; r < 4; r++) {
        float lt = l_[r];
        lt += __shfl_xor(lt, 1);
        lt += __shfl_xor(lt, 2);
        lt += __shfl_xor(lt, 4);
        lt += __shfl_xor(lt, 8);
        float inv = 1.0f / lt;
        int row = wq * 16 + l4 * 4 + r;
        int rx = row & 7, b64 = row * 64, wi = l15 & 7, hi = l15 >> 3;
#pragma unroll
        for (int j = 0; j < 4; j++) {
            int cnk = 2 * j + hi;    // 0..7 (half 0)
            Ps[b64 + ((cnk ^ rx) * 8) + wi] = f2bf(oacc[j][r] * inv);
        }
    }
    __syncthreads();
    {
        int r = tid >> 2, ch = (tid & 3) * 2;
        u16* dst = o + hb + (size_t)(q0 + r) * Cch;
        *(int4*)(dst + ch * 8)       = *(const int4*)&Ps[psw(r, ch)];
        *(int4*)(dst + (ch + 1) * 8) = *(const int4*)&Ps[psw(r, ch + 1)];
    }
}

// ---------------- final: out(B,C,S) = tmp(B,S,C bf16)^T + x ----------------
__global__ __launch_bounds__(256) void final_out_bf(const u16* __restrict__ tmp,
                                                    const float* __restrict__ x,
                                                    float* __restrict__ outp) {
    __shared__ float tile[32][33];
    int b = blockIdx.z, c0 = blockIdx.y * 32, s0 = blockIdx.x * 32;
    int tx = threadIdx.x, ty = threadIdx.y;
#pragma unroll
    for (int i = 0; i < 4; i++) {
        int s = s0 + ty + i * 8;
        tile[ty + i * 8][tx] = bf2f(tmp[((size_t)b * Ss + s) * Cch + c0 + tx]);
    }
    __syncthreads();
#pragma unroll
    for (int i = 0; i < 4; i++) {
        int c = c0 + ty + i * 8;
        size_t idx = ((size_t)b * Cch + c) * Ss + s0 + tx;
        outp[idx] = tile[tx][ty + i * 8] + x[idx];
    }
}

extern "C" void kernel_launch(void* const* d_in, const int* in_sizes, int n_in,
                              void* d_out, int out_size, void* d_ws, size_t ws_size,
                              hipStream_t stream) {
    (void)in_sizes; (void)n_in; (void)out_size; (void)ws_size;
    const float* x      = (const float*)d_in[0];
    const float* gn_w   = (const float*)d_in[1];
    const float* gn_b   = (const float*)d_in[2];
    const float* pin_w  = (const float*)d_in[3];
    const float* pin_b  = (const float*)d_in[4];
    const float* ln1_w  = (const float*)d_in[5];
    const float* ln1_b  = (const float*)d_in[6];
    const float* wq     = (const float*)d_in[7];
    const float* wk     = (const float*)d_in[8];
    const float* wv     = (const float*)d_in[9];
    const float* wo     = (const float*)d_in[10];
    const float* bo     = (const float*)d_in[11];
    const float* ln3_w  = (const float*)d_in[12];
    const float* ln3_b  = (const float*)d_in[13];
    const float* wg     = (const float*)d_in[14];
    const float* bg     = (const float*)d_in[15];
    const float* wd     = (const float*)d_in[16];
    const float* bd     = (const float*)d_in[17];
    const float* pout_w = (const float*)d_in[18];
    const float* pout_b = (const float*)d_in[19];
    float* out = (float*)d_out;

    // ---- workspace layout (bytes) ----
    char* W = (char*)d_ws;
    u16* tb        = (u16*)W;                                     // t residual, bf16, 16.78 MB
    float* tmp_f32 = (float*)(W + 33554432);                      // vtb region
    u16* qb    = (u16*)(W + 67108864);                            // 16.78 MB (qb,kb,vb contiguous)
    u16* kb    = qb + 8388608;
    u16* vb    = kb + 8388608;
    u16* attnb = vb + 8388608;
    u16* Xb    = attnb + 8388608;                                 // 16.78 MB
    float* stats = (float*)(W + 67108864 + 5ull * 16777216);      // 2 KB (256 partial pairs)
    u16* wbase = (u16*)(W + 67108864 + 5ull * 16777216 + 2048);
    u16* pinB  = wbase;                 // 512*512  (already [N][K])
    u16* poutB = pinB  + 262144;
    u16* wqT   = poutB + 262144;        // [512][512] transposed, scaled by QSCL
    u16* wkT   = wqT   + 262144;        // contiguous with wqT -> [1536][512] for fused qkv
    u16* wvT   = wkT   + 262144;
    u16* woT   = wvT   + 262144;
    u16* wgT   = woT   + 262144;        // [4096][512]
    u16* wdT   = wgT   + 2097152;       // [512][2048]
    u16* ag    = qb;                    // R x 2048 bf16, aliases qb..attnb (dead by then)
    u16* vtb   = (u16*)tmp_f32;         // V^T [b*8+h][64][1024]

    dim3 tb8(32, 8);

    // fused: GN partial stats (256 blocks) + all weight prep (4608 blocks), 1 launch
    prep_all<<<4864, tb8, 0, stream>>>(x, stats, pin_w, pout_w, pinB, poutB,
                                       wq, wk, wv, wo, wqT, wkT, wvT, woT,
                                       wg, wgT, wd, wdT);

    // h = GN(x) transposed -> Xb (bf16); combines stat partials
    gn_apply_t_bf<<<dim3(32, 16, 16), tb8, 0, stream>>>(x, stats, gn_w, gn_b, Xb);

    // t = h @ pin_w^T + pin_b -> tb (bf16)
    mfma_gemm<6><<<dim3(4, 64), 512, 0, stream>>>(Xb, pinB, pin_b, nullptr, tb, 512, 512);
    // tn = ln1(t) -> Xb
    layer_norm_rows_bf<<<4096, 256, 0, stream>>>(tb, ln1_w, ln1_b, Xb);
    // fused q(scaled)/k/v: N=1536, routed to qb/kb/vb
    mfma_gemm<8><<<dim3(12, 64), 512, 0, stream>>>(Xb, wqT, nullptr, nullptr, qb, 512, 1536);
    // per-head V transpose -> vtb
    vtrans<<<dim3(16, 8, 16), 256, 0, stream>>>(vb, vtb);
    // attention (MFMA, QBLK=128, KVBLK=128, prefetched, defer-max) -> attnb
    flash_attn_mfma<<<dim3(8, 8, 16), 512, 0, stream>>>(qb, kb, vtb, attnb);
    // t += attn @ wo + bo (bf16 in-place on tb)
    mfma_gemm<7><<<dim3(4, 64), 512, 0, stream>>>(attnb, woT, bo, nullptr, tb, 512, 512);
    // tn3 = ln3(t) -> Xb
    layer_norm_rows_bf<<<4096, 256, 0, stream>>>(tb, ln3_w, ln3_b, Xb);
    // ag = a * gelu(g) (bf16), aliases q/k/v/attn space
    geglu_mfma<<<dim3(32, 64), 512, 0, stream>>>(Xb, wgT, bg, ag);
    // t += ag @ wd + bd (bf16 in-place on tb)
    mfma_gemm<7><<<dim3(4, 64), 512, 0, stream>>>(ag, wdT, bd, nullptr, tb, 2048, 512);
    // tmp = t @ pout_w^T + pout_b -> Xb (bf16)
    mfma_gemm<6><<<dim3(4, 64), 512, 0, stream>>>(tb, poutB, pout_b, nullptr, Xb, 512, 512);
    // out = tmp^T + x
    final_out_bf<<<dim3(32, 16, 16), tb8, 0, stream>>>(Xb, x, out);
}